// Round 7
// baseline (570.575 us; speedup 1.0000x reference)
//
#include <hip/hip_runtime.h>
#include <hip/hip_fp16.h>
#include <math.h>

// ---------------------------------------------------------------------------
// NetGlobGATFix. R23: fuse attention into the gather (one edge pass/layer).
//   - Layers 1-4: gat_fused computes p=exp(lrelu(es[src]+ed[n])) in-kernel.
//     Lane j of a node's TPN-lane group owns (edge j/H, head j%H) for the
//     p/exp (no duplication), broadcasts alpha via segment __shfl, and
//     accumulates z with __shfl_xor stride-H reduction. zinv applied in the
//     epilogue as before. Kills 4 attn dispatches + ~40MB palpha round-trip.
//   - L0 (TPN=12, irregular) keeps the attn+palpha path.
//   - L4 keeps the fused final (W5 dot + wave reduce + mask) epilogue.
//   - acc order per (h,ch) unchanged; z summation order regrouped by lane
//     class (fp diff ~1e-7 in zinv, inside tolerance).
//   - Everything else identical to R22 (554.2us; R21 549.7).
// ---------------------------------------------------------------------------

#define DEVFN static __device__ __forceinline__

typedef __attribute__((ext_vector_type(8))) _Float16 half8;
typedef __attribute__((ext_vector_type(4))) _Float16 half4v;
typedef __attribute__((ext_vector_type(4))) float f32x4;

DEVFN float selu_f(float v) {
    const float scale = 1.0507009873554805f;
    const float alpha = 1.6732632423543772f;
    return v > 0.f ? scale * v : scale * alpha * (expf(v) - 1.f);
}

DEVFN float lrelu02(float v) { return v > 0.f ? v : 0.2f * v; }

// ---------------- CNN (padded 66x66 layout) ----------------
#define PST 66
#define PSZ (66 * 66)

__global__ void pad_input(const float* __restrict__ cf, float* __restrict__ out) {
    int t = blockIdx.x * blockDim.x + threadIdx.x;
    if (t >= 4 * 4096) return;
    int c = t >> 12, pix = t & 4095;
    int y = pix >> 6, x = pix & 63;
    out[c * PSZ + (y + 1) * PST + (x + 1)] = cf[t];
}

template <int CIN>
__global__ __launch_bounds__(256) void conv3x3_pad(const float* __restrict__ in,
                                                   const float* __restrict__ w,
                                                   const float* __restrict__ b,
                                                   float* __restrict__ out) {
    int x  = threadIdx.x & 63;
    int yg = threadIdx.x >> 6;
    int y  = blockIdx.x * 4 + yg;          // 0..63
    int co = blockIdx.y;
    float acc = b[co];
    const float* wp = w + (size_t)co * CIN * 9;
#pragma unroll 4
    for (int ci = 0; ci < CIN; ++ci) {
        const float* ip = in + ci * PSZ + y * PST + x;
        const float* wr = wp + ci * 9;
        acc += wr[0] * ip[0]           + wr[1] * ip[1]           + wr[2] * ip[2]
             + wr[3] * ip[PST]         + wr[4] * ip[PST + 1]     + wr[5] * ip[PST + 2]
             + wr[6] * ip[2 * PST]     + wr[7] * ip[2 * PST + 1] + wr[8] * ip[2 * PST + 2];
    }
    out[(size_t)co * PSZ + (y + 1) * PST + (x + 1)] = selu_f(acc);
}

__global__ void avgpool_c(const float* __restrict__ in, float* __restrict__ gfeat) {
    int c = blockIdx.x;            // 24 blocks
    int t = threadIdx.x;           // 256 threads
    float s = 0.f;
    for (int i = t; i < 4096; i += 256) {
        int y = i >> 6, x = i & 63;
        s += in[c * PSZ + (y + 1) * PST + (x + 1)];
    }
#pragma unroll
    for (int off = 32; off >= 1; off >>= 1) s += __shfl_xor(s, off);
    __shared__ float red[4];
    int wave = t >> 6, lane = t & 63;
    if (lane == 0) red[wave] = s;
    __syncthreads();
    if (t == 0) gfeat[c] = (red[0] + red[1] + red[2] + red[3]) * (1.f / 4096.f);
}

// ---------------- node feature init (padded to 48 ch, fp16) + masks ---------
__global__ void build_h0(const float* __restrict__ x, const float* __restrict__ gfeat,
                         __half* __restrict__ h0f, unsigned* __restrict__ masks, int N) {
    int n = blockIdx.x * blockDim.x + threadIdx.x;
    if (n >= N) return;
    float x0 = x[n * 10 + 0], x1 = x[n * 10 + 1];
    unsigned mk = (x0 == 1.f ? 1u : 0u) | (x0 == 0.f ? 2u : 0u) |
                  (x1 == 0.f ? 4u : 0u) | (x1 == 1.f ? 8u : 0u);
    masks[n] = mk;
    __half* hq = h0f + (size_t)n * 48;
#pragma unroll
    for (int j = 0; j < 48; ++j) {
        float v = (j < 24) ? gfeat[j] : (j < 34 ? x[n * 10 + (j - 24)] : 0.f);
        hq[j] = __float2half(v);
    }
}

// ---------------- CSR build (parallel scan) ----------------
__global__ void count_dst(const int* __restrict__ ei, int* __restrict__ cnt, int E, int N) {
    int t = blockIdx.x * blockDim.x + threadIdx.x;
    if (t >= E + N) return;
    int dst = (t < E) ? ei[E + t] : (t - E);
    atomicAdd(&cnt[dst], 1);
}

__global__ void scan_blocks(const int* __restrict__ cnt, int* __restrict__ pref,
                            int* __restrict__ bsums, int n) {
    __shared__ int sdata[256];
    int i = blockIdx.x * 256 + threadIdx.x;
    int v = (i < n) ? cnt[i] : 0;
    sdata[threadIdx.x] = v;
    __syncthreads();
    for (int off = 1; off < 256; off <<= 1) {
        int tmp = (threadIdx.x >= off) ? sdata[threadIdx.x - off] : 0;
        __syncthreads();
        sdata[threadIdx.x] += tmp;
        __syncthreads();
    }
    if (i < n) pref[i] = sdata[threadIdx.x] - v;
    if (threadIdx.x == 255) bsums[blockIdx.x] = sdata[255];
}

__global__ void scan_sums(int* __restrict__ bsums, int nb) {
    int tid = threadIdx.x;                 // 64
    int orig = (tid < nb) ? bsums[tid] : 0;
    int v = orig;
#pragma unroll
    for (int off = 1; off < 64; off <<= 1) {
        int u = __shfl_up(v, off);
        if (tid >= off) v += u;
    }
    if (tid < nb) bsums[tid] = v - orig;
}

__global__ void scan_apply(const int* __restrict__ pref, const int* __restrict__ bsums,
                           int* __restrict__ indptr, int* __restrict__ cursor,
                           int n, int total) {
    int i = blockIdx.x * 256 + threadIdx.x;
    if (i == 0) indptr[n] = total;
    if (i >= n) return;
    int e = bsums[blockIdx.x] + pref[i];
    indptr[i] = e;
    cursor[i] = e;
}

__global__ void scatter_edges(const int* __restrict__ ei, int* __restrict__ cursor,
                              int* __restrict__ col, int E, int N) {
    int t = blockIdx.x * blockDim.x + threadIdx.x;
    if (t >= E + N) return;
    int src, dst;
    if (t < E) { src = ei[t]; dst = ei[E + t]; }
    else       { src = dst = t - E; }
    int pos = atomicAdd(&cursor[dst], 1);
    col[pos] = src;
}

// ---------------- fused one-shot weight prep --------------------------------
// bt layout per layer: bt[btOff + m*KA + h*Kp + k] = fp16(W[k*HC + h*C + m])
// wesed[weOff + k*2H + o] = sum_c W[k,h*C+c]*a[h,c]  (h=o%H, a=as/ad by o<H).
// wstack (layer 4, C=2): wstack[(h*Kp+k)*2+c] = W4[k*32 + h*2 + c].
__global__ __launch_bounds__(256) void prep_all(
        const float* __restrict__ W0, const float* __restrict__ W1,
        const float* __restrict__ W2, const float* __restrict__ W3,
        const float* __restrict__ W4,
        const float* __restrict__ as0, const float* __restrict__ as1,
        const float* __restrict__ as2, const float* __restrict__ as3,
        const float* __restrict__ as4,
        const float* __restrict__ ad0, const float* __restrict__ ad1,
        const float* __restrict__ ad2, const float* __restrict__ ad3,
        const float* __restrict__ ad4,
        unsigned short* __restrict__ bt, float* __restrict__ wesed,
        float* __restrict__ wstack) {
    const int Kc[5]  = {34, 64, 128, 256, 128};
    const int Kpc[5] = {48, 64, 128, 256, 128};
    const int Hc[5]  = {8, 16, 8, 8, 16};
    const int Cc[5]  = {64, 128, 256, 128, 2};
    const int HCc[5] = {512, 2048, 2048, 1024, 32};
    const int KAc[5] = {384, 1024, 1024, 2048, 2048};
    const int btOff[5] = {0, 24576, 155648, 417792, 679936};
    const int weOff[5] = {0, 768, 2816, 4864, 8960};

    int b = blockIdx.x, tid = threadIdx.x;

    if (b < 168) {
        // ---- LDS-tiled transpose, one (layer, head, 64x64 tile) per block --
        int lyr, tloc;
        if (b < 8)        { lyr = 0; tloc = b; }
        else if (b < 40)  { lyr = 1; tloc = b - 8; }
        else if (b < 104) { lyr = 2; tloc = b - 40; }
        else              { lyr = 3; tloc = b - 104; }
        const int ktl[4] = {1, 1, 2, 4};   // ceil(Kp/64)
        const int mtl[4] = {1, 2, 4, 2};   // ceil(C/64)
        int kt = ktl[lyr], mt = mtl[lyr];
        int per_h = kt * mt;
        int h = tloc / per_h, r = tloc - h * per_h;
        int ki = r % kt, mi = r / kt;
        int k0 = ki * 64, m0 = mi * 64;
        int K = Kc[lyr], Kp = Kpc[lyr], C = Cc[lyr], HC = HCc[lyr], KA = KAc[lyr];
        const float* W;
        if (lyr == 0) W = W0; else if (lyr == 1) W = W1;
        else if (lyr == 2) W = W2; else W = W3;

        __shared__ float tile[64][65];
        int c = tid & 63, rg = tid >> 6;
        for (int r2 = rg; r2 < 64; r2 += 4) {       // coalesced 256B reads
            int k = k0 + r2, m = m0 + c;
            float v = (k < K && m < C) ? W[(size_t)k * HC + h * C + m] : 0.f;
            tile[r2][c] = v;
        }
        __syncthreads();
        unsigned short* bp = bt + btOff[lyr];
        for (int mr = rg; mr < 64; mr += 4) {       // coalesced 128B fp16 writes
            int m = m0 + mr, k = k0 + c;
            if (m < C && k < Kp)
                bp[(size_t)m * KA + h * Kp + k] =
                    __half_as_ushort(__float2half(tile[c][mr]));
        }
    } else if (b < 184) {
        // ---- wstack for layer 4 (C=2): 4096 outputs ----
        int u = (b - 168) * 256 + tid;              // Kp=128, H=16, HC=32
        int cc = u & 1, rr = u >> 1;
        int h = rr >> 7, k = rr & 127;
        wstack[u] = W4[k * 32 + h * 2 + cc];
    } else {
        // ---- wesed dots: sizes {768,2048,2048,4096,4096} -> 51 blocks ----
        int wb = b - 184;
        int lyr, u0;
        if (wb < 3)       { lyr = 0; u0 = wb * 256; }
        else if (wb < 11) { lyr = 1; u0 = (wb - 3) * 256; }
        else if (wb < 19) { lyr = 2; u0 = (wb - 11) * 256; }
        else if (wb < 35) { lyr = 3; u0 = (wb - 19) * 256; }
        else              { lyr = 4; u0 = (wb - 35) * 256; }
        int u = u0 + tid;
        int K = Kc[lyr], Kp = Kpc[lyr], H = Hc[lyr], C = Cc[lyr], HC = HCc[lyr];
        int H2 = 2 * H;
        if (u < Kp * H2) {
            int k = u / H2, o = u - k * H2;
            float s = 0.f;
            if (k < K) {
                int h = (o < H) ? o : o - H;
                const float *W, *as_, *ad_;
                if (lyr == 0)      { W = W0; as_ = as0; ad_ = ad0; }
                else if (lyr == 1) { W = W1; as_ = as1; ad_ = ad1; }
                else if (lyr == 2) { W = W2; as_ = as2; ad_ = ad2; }
                else if (lyr == 3) { W = W3; as_ = as3; ad_ = ad3; }
                else               { W = W4; as_ = as4; ad_ = ad4; }
                const float* av = ((o < H) ? as_ : ad_) + h * C;
                const float* wp = W + (size_t)k * HC + h * C;
#pragma unroll 4
                for (int c2 = 0; c2 < C; ++c2) s += wp[c2] * av[c2];
            }
            wesed[weOff[lyr] + u] = s;
        }
    }
}

// ---------------- es/ed: esed[n, o] = hin16[n,:] @ wesed[:,o], o < 2H -------
__global__ void esed_kernel(const __half* __restrict__ hin, const float* __restrict__ wesed,
                            float* __restrict__ esed, int N, int Kp, int H2) {
    int t = blockIdx.x * blockDim.x + threadIdx.x;
    if (t >= N * H2) return;
    int n = t / H2, o = t - n * H2;
    const __half2* hp = (const __half2*)(hin + (size_t)n * Kp);
    float s = 0.f;
    for (int k2 = 0; k2 < Kp / 2; ++k2) {
        float2 f = __half22float2(hp[k2]);
        s += f.x * wesed[(2 * k2) * H2 + o] + f.y * wesed[(2 * k2 + 1) * H2 + o];
    }
    esed[t] = s;
}

// -------- attention (layer 0 only): single pass, 4-deep ---------------------
__global__ void attn_kernel(const float* __restrict__ esed,
                            const int* __restrict__ indptr, const int* __restrict__ col,
                            float* __restrict__ palpha, float* __restrict__ zinv,
                            int N, int H) {
    int t = blockIdx.x * blockDim.x + threadIdx.x;
    if (t >= N * H) return;
    int n = t / H, h = t - n * H;
    int H2 = 2 * H;
    float edv = esed[n * H2 + H + h];
    int beg = indptr[n], end = indptr[n + 1];
    float z = 0.f;
    int i = beg;
    for (; i + 3 < end; i += 4) {
        int s0 = col[i], s1 = col[i + 1], s2 = col[i + 2], s3 = col[i + 3];
        float e0 = esed[s0 * H2 + h];
        float e1 = esed[s1 * H2 + h];
        float e2 = esed[s2 * H2 + h];
        float e3 = esed[s3 * H2 + h];
        float p0 = expf(lrelu02(e0 + edv));
        float p1 = expf(lrelu02(e1 + edv));
        float p2 = expf(lrelu02(e2 + edv));
        float p3 = expf(lrelu02(e3 + edv));
        palpha[(size_t)(i + 0) * H + h] = p0;
        palpha[(size_t)(i + 1) * H + h] = p1;
        palpha[(size_t)(i + 2) * H + h] = p2;
        palpha[(size_t)(i + 3) * H + h] = p3;
        z += p0; z += p1; z += p2; z += p3;
    }
    for (; i < end; ++i) {
        float e = lrelu02(esed[col[i] * H2 + h] + edv);
        float p = expf(e);
        palpha[(size_t)i * H + h] = p;
        z += p;
    }
    zinv[t] = (1.f / H) / (z + 1e-16f);
}

// -------- gather: half4 loads, 4-deep (layer 0, palpha path) ----------------
template <int H, int KP, int NPB>
__global__ __launch_bounds__(NPB * KP / 4) void gat_gather4(
        const __half* __restrict__ hinf, const float* __restrict__ palpha,
        const float* __restrict__ zinv, const int* __restrict__ indptr,
        const int* __restrict__ col, __half* __restrict__ g, int N) {
    const int TPN = KP / 4;
    int sub = threadIdx.x / TPN;
    int j   = threadIdx.x % TPN;
    int n = blockIdx.x * NPB + sub;
    if (n >= N) return;
    int c0 = j * 4;
    float acc[H][4];
#pragma unroll
    for (int h = 0; h < H; ++h)
#pragma unroll
        for (int t = 0; t < 4; ++t) acc[h][t] = 0.f;

    int beg = indptr[n], end = indptr[n + 1];
    int i = beg;
    for (; i + 3 < end; i += 4) {
        int s0 = col[i], s1 = col[i + 1], s2 = col[i + 2], s3 = col[i + 3];
        half4v hv0 = *(const half4v*)(hinf + (size_t)s0 * KP + c0);
        half4v hv1 = *(const half4v*)(hinf + (size_t)s1 * KP + c0);
        half4v hv2 = *(const half4v*)(hinf + (size_t)s2 * KP + c0);
        half4v hv3 = *(const half4v*)(hinf + (size_t)s3 * KP + c0);
#pragma unroll
        for (int e = 0; e < 4; ++e) {
            half4v hv = (e == 0) ? hv0 : (e == 1) ? hv1 : (e == 2) ? hv2 : hv3;
            float f[4] = {(float)hv[0], (float)hv[1], (float)hv[2], (float)hv[3]};
            const float2* ap = (const float2*)(palpha + (size_t)(i + e) * H);
#pragma unroll
            for (int h2 = 0; h2 < H / 2; ++h2) {
                float2 aa = ap[h2];
#pragma unroll
                for (int t = 0; t < 4; ++t) {
                    acc[2 * h2 + 0][t] += aa.x * f[t];
                    acc[2 * h2 + 1][t] += aa.y * f[t];
                }
            }
        }
    }
    for (; i < end; ++i) {
        int src = col[i];
        half4v hv = *(const half4v*)(hinf + (size_t)src * KP + c0);
        float f[4] = {(float)hv[0], (float)hv[1], (float)hv[2], (float)hv[3]};
        const float2* ap = (const float2*)(palpha + (size_t)i * H);
#pragma unroll
        for (int h2 = 0; h2 < H / 2; ++h2) {
            float2 aa = ap[h2];
#pragma unroll
            for (int t = 0; t < 4; ++t) {
                acc[2 * h2 + 0][t] += aa.x * f[t];
                acc[2 * h2 + 1][t] += aa.y * f[t];
            }
        }
    }

    __half* gp = g + (size_t)n * (H * KP) + c0;
#pragma unroll
    for (int h = 0; h < H; ++h) {
        float zf = zinv[n * H + h];
        __half2 lo = __floats2half2_rn(acc[h][0] * zf, acc[h][1] * zf);
        __half2 hi = __floats2half2_rn(acc[h][2] * zf, acc[h][3] * zf);
        union { __half2 h2[2]; float2 f2; } u;
        u.h2[0] = lo; u.h2[1] = hi;
        *(float2*)(gp + h * KP) = u.f2;
    }
}

// -------- fused attention+gather (layers 1-4) -------------------------------
// Node group = TPN = KP/CH lanes (32 or 64, lane-aligned). Per chunk of
// EC = TPN/H edges: lane j computes p for (edge j/H, head j%H) -- exp count
// is E*H with no duplication -- then alphas broadcast via segment __shfl.
// z accumulated per lane-class, reduced by __shfl_xor strides H,2H,...
// FINAL: dot with W5 + full-wave reduce + boundary mask (layer 4, C=2).
template <int H, int KP, int CH, int NPB, int FINAL>
__global__ __launch_bounds__(NPB * (KP / CH)) void gat_fused(
        const __half* __restrict__ hinf, const float* __restrict__ esed,
        const int* __restrict__ indptr, const int* __restrict__ col,
        __half* __restrict__ g,
        const float* __restrict__ W5, const float* __restrict__ b5,
        const unsigned* __restrict__ masks, const float* __restrict__ x,
        float* __restrict__ outp, int N) {
    const int TPN = KP / CH;          // 32 or 64
    const int EC  = TPN / H;          // edges per chunk
    const int H2  = 2 * H;
    int sub = threadIdx.x / TPN;
    int j   = threadIdx.x % TPN;
    int n = blockIdx.x * NPB + sub;
    if (n >= N) return;
    int se  = j / H;                  // my edge slot in chunk
    int myh = j % H;                  // my head for p
    int c0  = j * CH;                 // my channel chunk
    float edv = esed[n * H2 + H + myh];

    float acc[H][CH];
#pragma unroll
    for (int h = 0; h < H; ++h)
#pragma unroll
        for (int t = 0; t < CH; ++t) acc[h][t] = 0.f;
    float zloc = 0.f;

    int beg = indptr[n], deg = indptr[n + 1] - beg;
    for (int base = 0; base < deg; base += EC) {
        int ce = base + se;
        bool valid = ce < deg;
        int srcm = col[beg + (valid ? ce : 0)];
        float es = esed[srcm * H2 + myh];
        float p = valid ? expf(lrelu02(es + edv)) : 0.f;
        zloc += p;
#pragma unroll
        for (int e = 0; e < EC; ++e) {
            int idx = base + e;
            if (idx < deg) {                      // uniform within node group
                int src = col[beg + idx];
                float f[CH];
                if (CH == 2) {
                    __half2 hv = *(const __half2*)(hinf + (size_t)src * KP + c0);
                    float2 ff = __half22float2(hv);
                    f[0] = ff.x; f[1] = ff.y;
                } else {
                    half4v hv = *(const half4v*)(hinf + (size_t)src * KP + c0);
                    f[0] = (float)hv[0]; f[1] = (float)hv[1];
                    f[2] = (float)hv[2]; f[3] = (float)hv[3];
                }
#pragma unroll
                for (int h = 0; h < H; ++h) {
                    float alpha = __shfl(p, e * H + h, TPN);
#pragma unroll
                    for (int t = 0; t < CH; ++t) acc[h][t] += alpha * f[t];
                }
            }
        }
    }

    // z: reduce across the EC lanes of each head class (strides H, 2H, ...)
#pragma unroll
    for (int off = H; off < TPN; off <<= 1)
        zloc += __shfl_xor(zloc, off, TPN);
    float zinv_my = (1.f / H) / (zloc + 1e-16f);

    if (!FINAL) {
        __half* gp = g + (size_t)n * (H * KP) + c0;
#pragma unroll
        for (int h = 0; h < H; ++h) {
            float zf = __shfl(zinv_my, h, TPN);   // lane h holds class h
            if (CH == 2) {
                *(__half2*)(gp + h * KP) =
                    __floats2half2_rn(acc[h][0] * zf, acc[h][1] * zf);
            } else {
                __half2 lo = __floats2half2_rn(acc[h][0] * zf, acc[h][1] * zf);
                __half2 hi = __floats2half2_rn(acc[h][2] * zf, acc[h][3] * zf);
                union { __half2 h2[2]; float2 f2; } u;
                u.h2[0] = lo; u.h2[1] = hi;
                *(float2*)(gp + h * KP) = u.f2;
            }
        }
    } else {
        // fused last layer (CH==2): a = sum_h zinv_h * (acc[h] . W5 cols)
        float a0 = 0.f, a1 = 0.f;
#pragma unroll
        for (int h = 0; h < H; ++h) {
            float zf = __shfl(zinv_my, h, TPN);
            const float* wp = W5 + (size_t)(h * KP + c0) * 2;
            float4 w = *(const float4*)(wp);
            a0 += zf * (acc[h][0] * w.x + acc[h][1] * w.z);
            a1 += zf * (acc[h][0] * w.y + acc[h][1] * w.w);
        }
#pragma unroll
        for (int off = 32; off >= 1; off >>= 1) {  // TPN=64 full wave
            a0 += __shfl_xor(a0, off);
            a1 += __shfl_xor(a1, off);
        }
        if (j == 0) {
            unsigned mk = masks[n];
            float v0 = x[n * 10 + 0] + selu_f(a0 + b5[0]);
            float v1 = x[n * 10 + 1] + selu_f(a1 + b5[1]);
            if (mk & 2u) v0 = 0.f; else if (mk & 1u) v0 = 1.f;
            if (mk & 8u) v1 = 1.f; else if (mk & 4u) v1 = 0.f;
            outp[n * 2 + 0] = v0;
            outp[n * 2 + 1] = v1;
        }
    }
}

// ---------------- LDS-staged f16 MFMA GEMM (64x64 tile, BK=64) --------------
#define LDP 72
__global__ __launch_bounds__(256) void gemm_lds(const __half* __restrict__ A,
                                                const unsigned short* __restrict__ Bhi,
                                                const float* __restrict__ bias,
                                                const unsigned* __restrict__ masks,
                                                __half* __restrict__ O16,
                                                int N, int K, int M) {
    __shared__ __half lA[64 * LDP], lB[64 * LDP];
    int tid = threadIdx.x;
    int wave = tid >> 6, lane = tid & 63;
    int ln16 = lane & 15, q = lane >> 4;
    int row0 = blockIdx.x * 64;
    int col0 = blockIdx.y * 64;

    int r0 = tid >> 3, r1 = r0 + 32;
    int ac = (tid & 7) * 8;                      // col offset in halves
    int ga0 = min(row0 + r0, N - 1);
    int ga1 = min(row0 + r1, N - 1);
    const __half* Bp = (const __half*)Bhi;
    const __half* a0p = A + (size_t)ga0 * K + ac;
    const __half* a1p = A + (size_t)ga1 * K + ac;
    const __half* b0p = Bp + (size_t)(col0 + r0) * K + ac;
    const __half* b1p = Bp + (size_t)(col0 + r1) * K + ac;

    half8 ra0 = *(const half8*)(a0p);
    half8 ra1 = *(const half8*)(a1p);
    half8 rb0 = *(const half8*)(b0p);
    half8 rb1 = *(const half8*)(b1p);

    f32x4 acc[4];
#pragma unroll
    for (int j = 0; j < 4; ++j) acc[j] = (f32x4){0.f, 0.f, 0.f, 0.f};

    for (int kc = 0; kc < K; kc += 64) {
        __syncthreads();
        *(half8*)(lA + r0 * LDP + ac) = ra0;
        *(half8*)(lA + r1 * LDP + ac) = ra1;
        *(half8*)(lB + r0 * LDP + ac) = rb0;
        *(half8*)(lB + r1 * LDP + ac) = rb1;
        __syncthreads();
        int kn = kc + 64;
        if (kn < K) {
            ra0 = *(const half8*)(a0p + kn);
            ra1 = *(const half8*)(a1p + kn);
            rb0 = *(const half8*)(b0p + kn);
            rb1 = *(const half8*)(b1p + kn);
        }
#pragma unroll
        for (int kk = 0; kk < 2; ++kk) {
            half8 af = *(const half8*)(lA + (wave * 16 + ln16) * LDP + kk * 32 + q * 8);
#pragma unroll
            for (int j = 0; j < 4; ++j) {
                half8 bf = *(const half8*)(lB + (j * 16 + ln16) * LDP + kk * 32 + q * 8);
                acc[j] = __builtin_amdgcn_mfma_f32_16x16x32_f16(af, bf, acc[j], 0, 0, 0);
            }
        }
    }

#pragma unroll
    for (int j = 0; j < 4; ++j) {
        int cc = col0 + j * 16 + ln16;
        float bv = bias[cc];
#pragma unroll
        for (int r = 0; r < 4; ++r) {
            int rr = row0 + wave * 16 + q * 4 + r;
            if (rr >= N) continue;
            float v = selu_f(acc[j][r] + bv);
            if (cc < 2) {
                unsigned mk = masks[rr];
                if (cc == 0) { if (mk & 2u) v = 0.f; else if (mk & 1u) v = 1.f; }
                else         { if (mk & 8u) v = 1.f; else if (mk & 4u) v = 0.f; }
            }
            O16[(size_t)rr * M + cc] = __float2half(v);
        }
    }
}

// ---------------------------------------------------------------------------
extern "C" void kernel_launch(void* const* d_in, const int* in_sizes, int n_in,
                              void* d_out, int out_size, void* d_ws, size_t ws_size,
                              hipStream_t stream) {
    const float* x   = (const float*)d_in[0];
    const int*   ei  = (const int*)d_in[1];
    const float* cf  = (const float*)d_in[2];
    const float* cw[4] = {(const float*)d_in[3], (const float*)d_in[5],
                          (const float*)d_in[7], (const float*)d_in[9]};
    const float* cb[4] = {(const float*)d_in[4], (const float*)d_in[6],
                          (const float*)d_in[8], (const float*)d_in[10]};
    const float* gw[5], *gas[5], *gad[5], *gb[5];
    for (int i = 0; i < 5; ++i) {
        gw[i]  = (const float*)d_in[11 + 4 * i];
        gas[i] = (const float*)d_in[12 + 4 * i];
        gad[i] = (const float*)d_in[13 + 4 * i];
        gb[i]  = (const float*)d_in[14 + 4 * i];
    }
    const int N = in_sizes[0] / 10;        // 10000
    const int E = in_sizes[1] / 2;         // 160000
    const int EN = E + N;
    const int NB = (N + 255) / 256;        // scan blocks (40)

    // ---- workspace carve-up ----
    char* base = (char*)d_ws;
    size_t off = 0;
    auto alloc = [&](size_t bytes) -> char* {
        char* p = base + off;
        off = (off + bytes + 255) & ~(size_t)255;
        return p;
    };
    float* cfp   = (float*)alloc((size_t)4 * PSZ * 4);
    float* c1p   = (float*)alloc((size_t)16 * PSZ * 4);
    float* c2p   = (float*)alloc((size_t)32 * PSZ * 4);
    float* c3p   = (float*)alloc((size_t)64 * PSZ * 4);
    float* c4p   = (float*)alloc((size_t)24 * PSZ * 4);
    float* gfeat = (float*)alloc(24 * 4);
    __half* hA16 = (__half*)alloc((size_t)N * 256 * 2);
    __half* hB16 = (__half*)alloc((size_t)N * 256 * 2);
    __half* g    = (__half*)alloc((size_t)N * 2048 * 2);
    float* esed  = (float*)alloc((size_t)N * 32 * 4);
    float* zinv  = (float*)alloc((size_t)N * 16 * 4);
    float* palpha = (float*)alloc((size_t)EN * 16 * 4);      // L0 numerators
    float* wesed = (float*)alloc((size_t)13056 * 4);         // all 5 layers
    float* wstack= (float*)alloc((size_t)2048 * 2 * 4);
    unsigned short* bt = (unsigned short*)alloc((size_t)679936 * 2);  // 4 GEMM layers
    unsigned* masks = (unsigned*)alloc((size_t)N * 4);
    int* cnt    = (int*)alloc((size_t)N * 4);
    int* pref   = (int*)alloc((size_t)N * 4);
    int* bsums  = (int*)alloc(64 * 4);
    int* indptr = (int*)alloc((size_t)(N + 1) * 4);
    int* cursor = (int*)alloc((size_t)N * 4);
    int* col    = (int*)alloc((size_t)EN * 4);
    (void)ws_size; // ~78 MB

    // ---- one-shot fused weight prep (all 5 layers) ----
    prep_all<<<235, 256, 0, stream>>>(gw[0], gw[1], gw[2], gw[3], gw[4],
                                      gas[0], gas[1], gas[2], gas[3], gas[4],
                                      gad[0], gad[1], gad[2], gad[3], gad[4],
                                      bt, wesed, wstack);

    // ---- CNN (padded layout; single memset zeroes all borders) ----
    hipMemsetAsync(cfp, 0, (size_t)140 * PSZ * 4, stream);
    pad_input<<<(4 * 4096 + 255) / 256, 256, 0, stream>>>(cf, cfp);
    conv3x3_pad<4><<<dim3(16, 16), 256, 0, stream>>>(cfp, cw[0], cb[0], c1p);
    conv3x3_pad<16><<<dim3(16, 32), 256, 0, stream>>>(c1p, cw[1], cb[1], c2p);
    conv3x3_pad<32><<<dim3(16, 64), 256, 0, stream>>>(c2p, cw[2], cb[2], c3p);
    conv3x3_pad<64><<<dim3(16, 24), 256, 0, stream>>>(c3p, cw[3], cb[3], c4p);
    avgpool_c<<<24, 256, 0, stream>>>(c4p, gfeat);

    // ---- h0 (padded to 48, fp16) + masks ----
    build_h0<<<(N + 255) / 256, 256, 0, stream>>>(x, gfeat, hA16, masks, N);

    // ---- CSR by dst (incl self loops), parallel scan ----
    hipMemsetAsync(cnt, 0, (size_t)N * 4, stream);
    count_dst<<<(EN + 255) / 256, 256, 0, stream>>>(ei, cnt, E, N);
    scan_blocks<<<NB, 256, 0, stream>>>(cnt, pref, bsums, N);
    scan_sums<<<1, 64, 0, stream>>>(bsums, NB);
    scan_apply<<<NB, 256, 0, stream>>>(pref, bsums, indptr, cursor, N, EN);
    scatter_edges<<<(EN + 255) / 256, 256, 0, stream>>>(ei, cursor, col, E, N);

    // ---- GAT layers ----
    const int Hs[5] = {8, 16, 8, 8, 16};
    const int Cs[5] = {64, 128, 256, 128, 2};
    const int Kp[5] = {48, 64, 128, 256, 128};
    const int btOffA[5] = {0, 24576, 155648, 417792, 0};
    const int weOffA[5] = {0, 768, 2816, 4864, 8960};

    const __half* hin16 = hA16;
    __half* hout16[4]  = {hB16, hA16, hB16, hA16};

    for (int lyr = 0; lyr < 5; ++lyr) {
        int KP = Kp[lyr], H = Hs[lyr], C = Cs[lyr];
        int KA = H * KP;
        esed_kernel<<<(N * 2 * H + 255) / 256, 256, 0, stream>>>(hin16, wesed + weOffA[lyr],
                                                                 esed, N, KP, 2 * H);
        if (lyr == 0) {
            attn_kernel<<<(N * H + 255) / 256, 256, 0, stream>>>(esed, indptr, col,
                                                                 palpha, zinv, N, H);
            gat_gather4<8, 48, 20><<<(N + 19) / 20, 240, 0, stream>>>(
                hin16, palpha, zinv, indptr, col, g, N);
        } else if (lyr == 1) {
            gat_fused<16, 64, 2, 8, 0><<<(N + 7) / 8, 256, 0, stream>>>(
                hin16, esed, indptr, col, g,
                nullptr, nullptr, nullptr, nullptr, nullptr, N);
        } else if (lyr == 2) {
            gat_fused<8, 128, 4, 8, 0><<<(N + 7) / 8, 256, 0, stream>>>(
                hin16, esed, indptr, col, g,
                nullptr, nullptr, nullptr, nullptr, nullptr, N);
        } else if (lyr == 3) {
            gat_fused<8, 256, 4, 4, 0><<<(N + 3) / 4, 256, 0, stream>>>(
                hin16, esed, indptr, col, g,
                nullptr, nullptr, nullptr, nullptr, nullptr, N);
        } else {
            gat_fused<16, 128, 2, 4, 1><<<(N + 3) / 4, 256, 0, stream>>>(
                hin16, esed, indptr, col, nullptr,
                wstack, gb[4], masks, x, (float*)d_out, N);
        }

        if (lyr < 4) {
            const unsigned short* btL = bt + btOffA[lyr];
            int gx = (N + 63) / 64;        // 157
            gemm_lds<<<dim3(gx, C / 64), 256, 0, stream>>>(g, btL, gb[lyr], masks,
                                                           hout16[lyr], N, KA, C);
            hin16 = hout16[lyr];
        }
    }
}

// Round 8
// 554.731 us; speedup vs baseline: 1.0286x; 1.0286x over previous
//
#include <hip/hip_runtime.h>
#include <hip/hip_fp16.h>
#include <math.h>

// ---------------------------------------------------------------------------
// NetGlobGATFix. R24: best-of R21/R22 (R23 shfl-fusion regressed, reverted).
//   - R23's gat_fused: H serial __shfl broadcasts per edge serialized the
//     VALU (62us on L4, 238 GB/s). Reverted to split attn(L0)/palpha path +
//     per-layer gather kernels.
//   - History arithmetic: R21->R22 swapped TWO things; net +4.5us implies
//     L1 gather4(half4, acc64) was ~25us FASTER than half2 gather. The acc-reg
//     stall was specific to the FINAL variant's epilogue pressure.
//   - R24 = R22 base (L4 gat_gather2f fused-final kept) + R21's L1
//     gat_gather4<16,64,16>. Everything else identical to R22 (554.2us;
//     R21 549.7us).
// ---------------------------------------------------------------------------

#define DEVFN static __device__ __forceinline__

typedef __attribute__((ext_vector_type(8))) _Float16 half8;
typedef __attribute__((ext_vector_type(4))) _Float16 half4v;
typedef __attribute__((ext_vector_type(4))) float f32x4;

DEVFN float selu_f(float v) {
    const float scale = 1.0507009873554805f;
    const float alpha = 1.6732632423543772f;
    return v > 0.f ? scale * v : scale * alpha * (expf(v) - 1.f);
}

DEVFN float lrelu02(float v) { return v > 0.f ? v : 0.2f * v; }

// ---------------- CNN (padded 66x66 layout) ----------------
#define PST 66
#define PSZ (66 * 66)

__global__ void pad_input(const float* __restrict__ cf, float* __restrict__ out) {
    int t = blockIdx.x * blockDim.x + threadIdx.x;
    if (t >= 4 * 4096) return;
    int c = t >> 12, pix = t & 4095;
    int y = pix >> 6, x = pix & 63;
    out[c * PSZ + (y + 1) * PST + (x + 1)] = cf[t];
}

template <int CIN>
__global__ __launch_bounds__(256) void conv3x3_pad(const float* __restrict__ in,
                                                   const float* __restrict__ w,
                                                   const float* __restrict__ b,
                                                   float* __restrict__ out) {
    int x  = threadIdx.x & 63;
    int yg = threadIdx.x >> 6;
    int y  = blockIdx.x * 4 + yg;          // 0..63
    int co = blockIdx.y;
    float acc = b[co];
    const float* wp = w + (size_t)co * CIN * 9;
#pragma unroll 4
    for (int ci = 0; ci < CIN; ++ci) {
        const float* ip = in + ci * PSZ + y * PST + x;
        const float* wr = wp + ci * 9;
        acc += wr[0] * ip[0]           + wr[1] * ip[1]           + wr[2] * ip[2]
             + wr[3] * ip[PST]         + wr[4] * ip[PST + 1]     + wr[5] * ip[PST + 2]
             + wr[6] * ip[2 * PST]     + wr[7] * ip[2 * PST + 1] + wr[8] * ip[2 * PST + 2];
    }
    out[(size_t)co * PSZ + (y + 1) * PST + (x + 1)] = selu_f(acc);
}

__global__ void avgpool_c(const float* __restrict__ in, float* __restrict__ gfeat) {
    int c = blockIdx.x;            // 24 blocks
    int t = threadIdx.x;           // 256 threads
    float s = 0.f;
    for (int i = t; i < 4096; i += 256) {
        int y = i >> 6, x = i & 63;
        s += in[c * PSZ + (y + 1) * PST + (x + 1)];
    }
#pragma unroll
    for (int off = 32; off >= 1; off >>= 1) s += __shfl_xor(s, off);
    __shared__ float red[4];
    int wave = t >> 6, lane = t & 63;
    if (lane == 0) red[wave] = s;
    __syncthreads();
    if (t == 0) gfeat[c] = (red[0] + red[1] + red[2] + red[3]) * (1.f / 4096.f);
}

// ---------------- node feature init (padded to 48 ch, fp16) + masks ---------
__global__ void build_h0(const float* __restrict__ x, const float* __restrict__ gfeat,
                         __half* __restrict__ h0f, unsigned* __restrict__ masks, int N) {
    int n = blockIdx.x * blockDim.x + threadIdx.x;
    if (n >= N) return;
    float x0 = x[n * 10 + 0], x1 = x[n * 10 + 1];
    unsigned mk = (x0 == 1.f ? 1u : 0u) | (x0 == 0.f ? 2u : 0u) |
                  (x1 == 0.f ? 4u : 0u) | (x1 == 1.f ? 8u : 0u);
    masks[n] = mk;
    __half* hq = h0f + (size_t)n * 48;
#pragma unroll
    for (int j = 0; j < 48; ++j) {
        float v = (j < 24) ? gfeat[j] : (j < 34 ? x[n * 10 + (j - 24)] : 0.f);
        hq[j] = __float2half(v);
    }
}

// ---------------- CSR build (parallel scan) ----------------
__global__ void count_dst(const int* __restrict__ ei, int* __restrict__ cnt, int E, int N) {
    int t = blockIdx.x * blockDim.x + threadIdx.x;
    if (t >= E + N) return;
    int dst = (t < E) ? ei[E + t] : (t - E);
    atomicAdd(&cnt[dst], 1);
}

__global__ void scan_blocks(const int* __restrict__ cnt, int* __restrict__ pref,
                            int* __restrict__ bsums, int n) {
    __shared__ int sdata[256];
    int i = blockIdx.x * 256 + threadIdx.x;
    int v = (i < n) ? cnt[i] : 0;
    sdata[threadIdx.x] = v;
    __syncthreads();
    for (int off = 1; off < 256; off <<= 1) {
        int tmp = (threadIdx.x >= off) ? sdata[threadIdx.x - off] : 0;
        __syncthreads();
        sdata[threadIdx.x] += tmp;
        __syncthreads();
    }
    if (i < n) pref[i] = sdata[threadIdx.x] - v;
    if (threadIdx.x == 255) bsums[blockIdx.x] = sdata[255];
}

__global__ void scan_sums(int* __restrict__ bsums, int nb) {
    int tid = threadIdx.x;                 // 64
    int orig = (tid < nb) ? bsums[tid] : 0;
    int v = orig;
#pragma unroll
    for (int off = 1; off < 64; off <<= 1) {
        int u = __shfl_up(v, off);
        if (tid >= off) v += u;
    }
    if (tid < nb) bsums[tid] = v - orig;
}

__global__ void scan_apply(const int* __restrict__ pref, const int* __restrict__ bsums,
                           int* __restrict__ indptr, int* __restrict__ cursor,
                           int n, int total) {
    int i = blockIdx.x * 256 + threadIdx.x;
    if (i == 0) indptr[n] = total;
    if (i >= n) return;
    int e = bsums[blockIdx.x] + pref[i];
    indptr[i] = e;
    cursor[i] = e;
}

__global__ void scatter_edges(const int* __restrict__ ei, int* __restrict__ cursor,
                              int* __restrict__ col, int E, int N) {
    int t = blockIdx.x * blockDim.x + threadIdx.x;
    if (t >= E + N) return;
    int src, dst;
    if (t < E) { src = ei[t]; dst = ei[E + t]; }
    else       { src = dst = t - E; }
    int pos = atomicAdd(&cursor[dst], 1);
    col[pos] = src;
}

// ---------------- fused one-shot weight prep --------------------------------
// bt layout per layer: bt[btOff + m*KA + h*Kp + k] = fp16(W[k*HC + h*C + m])
// wesed[weOff + k*2H + o] = sum_c W[k,h*C+c]*a[h,c]  (h=o%H, a=as/ad by o<H).
// wstack (layer 4, C=2): wstack[(h*Kp+k)*2+c] = W4[k*32 + h*2 + c].
__global__ __launch_bounds__(256) void prep_all(
        const float* __restrict__ W0, const float* __restrict__ W1,
        const float* __restrict__ W2, const float* __restrict__ W3,
        const float* __restrict__ W4,
        const float* __restrict__ as0, const float* __restrict__ as1,
        const float* __restrict__ as2, const float* __restrict__ as3,
        const float* __restrict__ as4,
        const float* __restrict__ ad0, const float* __restrict__ ad1,
        const float* __restrict__ ad2, const float* __restrict__ ad3,
        const float* __restrict__ ad4,
        unsigned short* __restrict__ bt, float* __restrict__ wesed,
        float* __restrict__ wstack) {
    const int Kc[5]  = {34, 64, 128, 256, 128};
    const int Kpc[5] = {48, 64, 128, 256, 128};
    const int Hc[5]  = {8, 16, 8, 8, 16};
    const int Cc[5]  = {64, 128, 256, 128, 2};
    const int HCc[5] = {512, 2048, 2048, 1024, 32};
    const int KAc[5] = {384, 1024, 1024, 2048, 2048};
    const int btOff[5] = {0, 24576, 155648, 417792, 679936};
    const int weOff[5] = {0, 768, 2816, 4864, 8960};

    int b = blockIdx.x, tid = threadIdx.x;

    if (b < 168) {
        // ---- LDS-tiled transpose, one (layer, head, 64x64 tile) per block --
        int lyr, tloc;
        if (b < 8)        { lyr = 0; tloc = b; }
        else if (b < 40)  { lyr = 1; tloc = b - 8; }
        else if (b < 104) { lyr = 2; tloc = b - 40; }
        else              { lyr = 3; tloc = b - 104; }
        const int ktl[4] = {1, 1, 2, 4};   // ceil(Kp/64)
        const int mtl[4] = {1, 2, 4, 2};   // ceil(C/64)
        int kt = ktl[lyr], mt = mtl[lyr];
        int per_h = kt * mt;
        int h = tloc / per_h, r = tloc - h * per_h;
        int ki = r % kt, mi = r / kt;
        int k0 = ki * 64, m0 = mi * 64;
        int K = Kc[lyr], Kp = Kpc[lyr], C = Cc[lyr], HC = HCc[lyr], KA = KAc[lyr];
        const float* W;
        if (lyr == 0) W = W0; else if (lyr == 1) W = W1;
        else if (lyr == 2) W = W2; else W = W3;

        __shared__ float tile[64][65];
        int c = tid & 63, rg = tid >> 6;
        for (int r2 = rg; r2 < 64; r2 += 4) {       // coalesced 256B reads
            int k = k0 + r2, m = m0 + c;
            float v = (k < K && m < C) ? W[(size_t)k * HC + h * C + m] : 0.f;
            tile[r2][c] = v;
        }
        __syncthreads();
        unsigned short* bp = bt + btOff[lyr];
        for (int mr = rg; mr < 64; mr += 4) {       // coalesced 128B fp16 writes
            int m = m0 + mr, k = k0 + c;
            if (m < C && k < Kp)
                bp[(size_t)m * KA + h * Kp + k] =
                    __half_as_ushort(__float2half(tile[c][mr]));
        }
    } else if (b < 184) {
        // ---- wstack for layer 4 (C=2): 4096 outputs ----
        int u = (b - 168) * 256 + tid;              // Kp=128, H=16, HC=32
        int cc = u & 1, rr = u >> 1;
        int h = rr >> 7, k = rr & 127;
        wstack[u] = W4[k * 32 + h * 2 + cc];
    } else {
        // ---- wesed dots: sizes {768,2048,2048,4096,4096} -> 51 blocks ----
        int wb = b - 184;
        int lyr, u0;
        if (wb < 3)       { lyr = 0; u0 = wb * 256; }
        else if (wb < 11) { lyr = 1; u0 = (wb - 3) * 256; }
        else if (wb < 19) { lyr = 2; u0 = (wb - 11) * 256; }
        else if (wb < 35) { lyr = 3; u0 = (wb - 19) * 256; }
        else              { lyr = 4; u0 = (wb - 35) * 256; }
        int u = u0 + tid;
        int K = Kc[lyr], Kp = Kpc[lyr], H = Hc[lyr], C = Cc[lyr], HC = HCc[lyr];
        int H2 = 2 * H;
        if (u < Kp * H2) {
            int k = u / H2, o = u - k * H2;
            float s = 0.f;
            if (k < K) {
                int h = (o < H) ? o : o - H;
                const float *W, *as_, *ad_;
                if (lyr == 0)      { W = W0; as_ = as0; ad_ = ad0; }
                else if (lyr == 1) { W = W1; as_ = as1; ad_ = ad1; }
                else if (lyr == 2) { W = W2; as_ = as2; ad_ = ad2; }
                else if (lyr == 3) { W = W3; as_ = as3; ad_ = ad3; }
                else               { W = W4; as_ = as4; ad_ = ad4; }
                const float* av = ((o < H) ? as_ : ad_) + h * C;
                const float* wp = W + (size_t)k * HC + h * C;
#pragma unroll 4
                for (int c2 = 0; c2 < C; ++c2) s += wp[c2] * av[c2];
            }
            wesed[weOff[lyr] + u] = s;
        }
    }
}

// ---------------- es/ed: esed[n, o] = hin16[n,:] @ wesed[:,o], o < 2H -------
__global__ void esed_kernel(const __half* __restrict__ hin, const float* __restrict__ wesed,
                            float* __restrict__ esed, int N, int Kp, int H2) {
    int t = blockIdx.x * blockDim.x + threadIdx.x;
    if (t >= N * H2) return;
    int n = t / H2, o = t - n * H2;
    const __half2* hp = (const __half2*)(hin + (size_t)n * Kp);
    float s = 0.f;
    for (int k2 = 0; k2 < Kp / 2; ++k2) {
        float2 f = __half22float2(hp[k2]);
        s += f.x * wesed[(2 * k2) * H2 + o] + f.y * wesed[(2 * k2 + 1) * H2 + o];
    }
    esed[t] = s;
}

// -------- attention: single pass, 4-deep gather pipeline --------------------
__global__ void attn_kernel(const float* __restrict__ esed,
                            const int* __restrict__ indptr, const int* __restrict__ col,
                            float* __restrict__ palpha, float* __restrict__ zinv,
                            int N, int H) {
    int t = blockIdx.x * blockDim.x + threadIdx.x;
    if (t >= N * H) return;
    int n = t / H, h = t - n * H;
    int H2 = 2 * H;
    float edv = esed[n * H2 + H + h];
    int beg = indptr[n], end = indptr[n + 1];
    float z = 0.f;
    int i = beg;
    for (; i + 3 < end; i += 4) {
        int s0 = col[i], s1 = col[i + 1], s2 = col[i + 2], s3 = col[i + 3];
        float e0 = esed[s0 * H2 + h];
        float e1 = esed[s1 * H2 + h];
        float e2 = esed[s2 * H2 + h];
        float e3 = esed[s3 * H2 + h];
        float p0 = expf(lrelu02(e0 + edv));
        float p1 = expf(lrelu02(e1 + edv));
        float p2 = expf(lrelu02(e2 + edv));
        float p3 = expf(lrelu02(e3 + edv));
        palpha[(size_t)(i + 0) * H + h] = p0;
        palpha[(size_t)(i + 1) * H + h] = p1;
        palpha[(size_t)(i + 2) * H + h] = p2;
        palpha[(size_t)(i + 3) * H + h] = p3;
        z += p0; z += p1; z += p2; z += p3;
    }
    for (; i < end; ++i) {
        float e = lrelu02(esed[col[i] * H2 + h] + edv);
        float p = expf(e);
        palpha[(size_t)i * H + h] = p;
        z += p;
    }
    zinv[t] = (1.f / H) / (z + 1e-16f);
}

// -------- gather: half4 (8B) loads, 4-deep ----------------------------------
template <int H, int KP, int NPB>
__global__ __launch_bounds__(NPB * KP / 4) void gat_gather4(
        const __half* __restrict__ hinf, const float* __restrict__ palpha,
        const float* __restrict__ zinv, const int* __restrict__ indptr,
        const int* __restrict__ col, __half* __restrict__ g, int N) {
    const int TPN = KP / 4;
    int sub = threadIdx.x / TPN;
    int j   = threadIdx.x % TPN;
    int n = blockIdx.x * NPB + sub;
    if (n >= N) return;
    int c0 = j * 4;
    float acc[H][4];
#pragma unroll
    for (int h = 0; h < H; ++h)
#pragma unroll
        for (int t = 0; t < 4; ++t) acc[h][t] = 0.f;

    int beg = indptr[n], end = indptr[n + 1];
    int i = beg;
    for (; i + 3 < end; i += 4) {
        int s0 = col[i], s1 = col[i + 1], s2 = col[i + 2], s3 = col[i + 3];
        half4v hv0 = *(const half4v*)(hinf + (size_t)s0 * KP + c0);
        half4v hv1 = *(const half4v*)(hinf + (size_t)s1 * KP + c0);
        half4v hv2 = *(const half4v*)(hinf + (size_t)s2 * KP + c0);
        half4v hv3 = *(const half4v*)(hinf + (size_t)s3 * KP + c0);
#pragma unroll
        for (int e = 0; e < 4; ++e) {
            half4v hv = (e == 0) ? hv0 : (e == 1) ? hv1 : (e == 2) ? hv2 : hv3;
            float f[4] = {(float)hv[0], (float)hv[1], (float)hv[2], (float)hv[3]};
            const float2* ap = (const float2*)(palpha + (size_t)(i + e) * H);
#pragma unroll
            for (int h2 = 0; h2 < H / 2; ++h2) {
                float2 aa = ap[h2];
#pragma unroll
                for (int t = 0; t < 4; ++t) {
                    acc[2 * h2 + 0][t] += aa.x * f[t];
                    acc[2 * h2 + 1][t] += aa.y * f[t];
                }
            }
        }
    }
    for (; i < end; ++i) {
        int src = col[i];
        half4v hv = *(const half4v*)(hinf + (size_t)src * KP + c0);
        float f[4] = {(float)hv[0], (float)hv[1], (float)hv[2], (float)hv[3]};
        const float2* ap = (const float2*)(palpha + (size_t)i * H);
#pragma unroll
        for (int h2 = 0; h2 < H / 2; ++h2) {
            float2 aa = ap[h2];
#pragma unroll
            for (int t = 0; t < 4; ++t) {
                acc[2 * h2 + 0][t] += aa.x * f[t];
                acc[2 * h2 + 1][t] += aa.y * f[t];
            }
        }
    }

    __half* gp = g + (size_t)n * (H * KP) + c0;
#pragma unroll
    for (int h = 0; h < H; ++h) {
        float zf = zinv[n * H + h];
        __half2 lo = __floats2half2_rn(acc[h][0] * zf, acc[h][1] * zf);
        __half2 hi = __floats2half2_rn(acc[h][2] * zf, acc[h][3] * zf);
        union { __half2 h2[2]; float2 f2; } u;
        u.h2[0] = lo; u.h2[1] = hi;
        *(float2*)(gp + h * KP) = u.f2;
    }
}

// -------- gather + fused final layer (H=16, half2: acc[16][2]=32) -----------
// TPN = KP/2 = 64 (full wave): thread j owns channels {2j, 2j+1}; epilogue
// dots acc with W5 and shfl-reduces over the 64-lane wave.
template <int H, int KP, int NPB>
__global__ __launch_bounds__(NPB * KP / 2) void gat_gather2f(
        const __half* __restrict__ hinf, const float* __restrict__ palpha,
        const float* __restrict__ zinv, const int* __restrict__ indptr,
        const int* __restrict__ col,
        const float* __restrict__ W5, const float* __restrict__ b5,
        const unsigned* __restrict__ masks, const float* __restrict__ x,
        float* __restrict__ outp, int N) {
    const int TPN = KP / 2;                 // 64
    int sub = threadIdx.x / TPN;
    int j   = threadIdx.x % TPN;
    int n = blockIdx.x * NPB + sub;
    if (n >= N) return;
    int c0 = j * 2;
    float acc[H][2];
#pragma unroll
    for (int h = 0; h < H; ++h) { acc[h][0] = 0.f; acc[h][1] = 0.f; }
    int beg = indptr[n], end = indptr[n + 1];
    int i = beg;
    for (; i + 3 < end; i += 4) {
        int s0 = col[i], s1 = col[i + 1], s2 = col[i + 2], s3 = col[i + 3];
        __half2 hv0 = *(const __half2*)(hinf + (size_t)s0 * KP + c0);
        __half2 hv1 = *(const __half2*)(hinf + (size_t)s1 * KP + c0);
        __half2 hv2 = *(const __half2*)(hinf + (size_t)s2 * KP + c0);
        __half2 hv3 = *(const __half2*)(hinf + (size_t)s3 * KP + c0);
        float2 fv[4] = {__half22float2(hv0), __half22float2(hv1),
                        __half22float2(hv2), __half22float2(hv3)};
#pragma unroll
        for (int e = 0; e < 4; ++e) {
            const float2* ap = (const float2*)(palpha + (size_t)(i + e) * H);
            float2 f = fv[e];
#pragma unroll
            for (int h2 = 0; h2 < H / 2; ++h2) {
                float2 aa = ap[h2];
                acc[2 * h2 + 0][0] += aa.x * f.x;
                acc[2 * h2 + 0][1] += aa.x * f.y;
                acc[2 * h2 + 1][0] += aa.y * f.x;
                acc[2 * h2 + 1][1] += aa.y * f.y;
            }
        }
    }
    for (; i < end; ++i) {
        int src = col[i];
        __half2 hv = *(const __half2*)(hinf + (size_t)src * KP + c0);
        float2 f = __half22float2(hv);
        const float2* ap = (const float2*)(palpha + (size_t)i * H);
#pragma unroll
        for (int h2 = 0; h2 < H / 2; ++h2) {
            float2 aa = ap[h2];
            acc[2 * h2 + 0][0] += aa.x * f.x;
            acc[2 * h2 + 0][1] += aa.x * f.y;
            acc[2 * h2 + 1][0] += aa.y * f.x;
            acc[2 * h2 + 1][1] += aa.y * f.y;
        }
    }

    // fused last layer: a = sum_h zinv_h * (acc[h][:] . W5[h*KP+c0+:, 0/1])
    float a0 = 0.f, a1 = 0.f;
#pragma unroll
    for (int h = 0; h < H; ++h) {
        float zf = zinv[n * H + h];
        const float* wp = W5 + (size_t)(h * KP + c0) * 2;
        float4 w = *(const float4*)(wp);   // [k=c0: c=0,1][k=c0+1: c=0,1]
        float p0 = acc[h][0] * w.x + acc[h][1] * w.z;
        float p1 = acc[h][0] * w.y + acc[h][1] * w.w;
        a0 += zf * p0;
        a1 += zf * p1;
    }
#pragma unroll
    for (int off = 32; off >= 1; off >>= 1) {   // TPN=64 = full wave
        a0 += __shfl_xor(a0, off);
        a1 += __shfl_xor(a1, off);
    }
    if (j == 0) {
        unsigned mk = masks[n];
        float v0 = x[n * 10 + 0] + selu_f(a0 + b5[0]);
        float v1 = x[n * 10 + 1] + selu_f(a1 + b5[1]);
        if (mk & 2u) v0 = 0.f; else if (mk & 1u) v0 = 1.f;
        if (mk & 8u) v1 = 1.f; else if (mk & 4u) v1 = 0.f;
        outp[n * 2 + 0] = v0;
        outp[n * 2 + 1] = v1;
    }
}

// ---------------- LDS-staged f16 MFMA GEMM (64x64 tile, BK=64) --------------
#define LDP 72
__global__ __launch_bounds__(256) void gemm_lds(const __half* __restrict__ A,
                                                const unsigned short* __restrict__ Bhi,
                                                const float* __restrict__ bias,
                                                const unsigned* __restrict__ masks,
                                                __half* __restrict__ O16,
                                                int N, int K, int M) {
    __shared__ __half lA[64 * LDP], lB[64 * LDP];
    int tid = threadIdx.x;
    int wave = tid >> 6, lane = tid & 63;
    int ln16 = lane & 15, q = lane >> 4;
    int row0 = blockIdx.x * 64;
    int col0 = blockIdx.y * 64;

    int r0 = tid >> 3, r1 = r0 + 32;
    int ac = (tid & 7) * 8;                      // col offset in halves
    int ga0 = min(row0 + r0, N - 1);
    int ga1 = min(row0 + r1, N - 1);
    const __half* Bp = (const __half*)Bhi;
    const __half* a0p = A + (size_t)ga0 * K + ac;
    const __half* a1p = A + (size_t)ga1 * K + ac;
    const __half* b0p = Bp + (size_t)(col0 + r0) * K + ac;
    const __half* b1p = Bp + (size_t)(col0 + r1) * K + ac;

    half8 ra0 = *(const half8*)(a0p);
    half8 ra1 = *(const half8*)(a1p);
    half8 rb0 = *(const half8*)(b0p);
    half8 rb1 = *(const half8*)(b1p);

    f32x4 acc[4];
#pragma unroll
    for (int j = 0; j < 4; ++j) acc[j] = (f32x4){0.f, 0.f, 0.f, 0.f};

    for (int kc = 0; kc < K; kc += 64) {
        __syncthreads();
        *(half8*)(lA + r0 * LDP + ac) = ra0;
        *(half8*)(lA + r1 * LDP + ac) = ra1;
        *(half8*)(lB + r0 * LDP + ac) = rb0;
        *(half8*)(lB + r1 * LDP + ac) = rb1;
        __syncthreads();
        int kn = kc + 64;
        if (kn < K) {
            ra0 = *(const half8*)(a0p + kn);
            ra1 = *(const half8*)(a1p + kn);
            rb0 = *(const half8*)(b0p + kn);
            rb1 = *(const half8*)(b1p + kn);
        }
#pragma unroll
        for (int kk = 0; kk < 2; ++kk) {
            half8 af = *(const half8*)(lA + (wave * 16 + ln16) * LDP + kk * 32 + q * 8);
#pragma unroll
            for (int j = 0; j < 4; ++j) {
                half8 bf = *(const half8*)(lB + (j * 16 + ln16) * LDP + kk * 32 + q * 8);
                acc[j] = __builtin_amdgcn_mfma_f32_16x16x32_f16(af, bf, acc[j], 0, 0, 0);
            }
        }
    }

#pragma unroll
    for (int j = 0; j < 4; ++j) {
        int cc = col0 + j * 16 + ln16;
        float bv = bias[cc];
#pragma unroll
        for (int r = 0; r < 4; ++r) {
            int rr = row0 + wave * 16 + q * 4 + r;
            if (rr >= N) continue;
            float v = selu_f(acc[j][r] + bv);
            if (cc < 2) {
                unsigned mk = masks[rr];
                if (cc == 0) { if (mk & 2u) v = 0.f; else if (mk & 1u) v = 1.f; }
                else         { if (mk & 8u) v = 1.f; else if (mk & 4u) v = 0.f; }
            }
            O16[(size_t)rr * M + cc] = __float2half(v);
        }
    }
}

// ---------------------------------------------------------------------------
extern "C" void kernel_launch(void* const* d_in, const int* in_sizes, int n_in,
                              void* d_out, int out_size, void* d_ws, size_t ws_size,
                              hipStream_t stream) {
    const float* x   = (const float*)d_in[0];
    const int*   ei  = (const int*)d_in[1];
    const float* cf  = (const float*)d_in[2];
    const float* cw[4] = {(const float*)d_in[3], (const float*)d_in[5],
                          (const float*)d_in[7], (const float*)d_in[9]};
    const float* cb[4] = {(const float*)d_in[4], (const float*)d_in[6],
                          (const float*)d_in[8], (const float*)d_in[10]};
    const float* gw[5], *gas[5], *gad[5], *gb[5];
    for (int i = 0; i < 5; ++i) {
        gw[i]  = (const float*)d_in[11 + 4 * i];
        gas[i] = (const float*)d_in[12 + 4 * i];
        gad[i] = (const float*)d_in[13 + 4 * i];
        gb[i]  = (const float*)d_in[14 + 4 * i];
    }
    const int N = in_sizes[0] / 10;        // 10000
    const int E = in_sizes[1] / 2;         // 160000
    const int EN = E + N;
    const int NB = (N + 255) / 256;        // scan blocks (40)

    // ---- workspace carve-up ----
    char* base = (char*)d_ws;
    size_t off = 0;
    auto alloc = [&](size_t bytes) -> char* {
        char* p = base + off;
        off = (off + bytes + 255) & ~(size_t)255;
        return p;
    };
    float* cfp   = (float*)alloc((size_t)4 * PSZ * 4);
    float* c1p   = (float*)alloc((size_t)16 * PSZ * 4);
    float* c2p   = (float*)alloc((size_t)32 * PSZ * 4);
    float* c3p   = (float*)alloc((size_t)64 * PSZ * 4);
    float* c4p   = (float*)alloc((size_t)24 * PSZ * 4);
    float* gfeat = (float*)alloc(24 * 4);
    __half* hA16 = (__half*)alloc((size_t)N * 256 * 2);
    __half* hB16 = (__half*)alloc((size_t)N * 256 * 2);
    __half* g    = (__half*)alloc((size_t)N * 2048 * 2);
    float* esed  = (float*)alloc((size_t)N * 32 * 4);
    float* zinv  = (float*)alloc((size_t)N * 16 * 4);
    float* palpha = (float*)alloc((size_t)EN * 16 * 4);      // fp32 numerators
    float* wesed = (float*)alloc((size_t)13056 * 4);         // all 5 layers
    float* wstack= (float*)alloc((size_t)2048 * 2 * 4);
    unsigned short* bt = (unsigned short*)alloc((size_t)679936 * 2);  // 4 GEMM layers
    unsigned* masks = (unsigned*)alloc((size_t)N * 4);
    int* cnt    = (int*)alloc((size_t)N * 4);
    int* pref   = (int*)alloc((size_t)N * 4);
    int* bsums  = (int*)alloc(64 * 4);
    int* indptr = (int*)alloc((size_t)(N + 1) * 4);
    int* cursor = (int*)alloc((size_t)N * 4);
    int* col    = (int*)alloc((size_t)EN * 4);
    (void)ws_size; // ~78 MB

    // ---- one-shot fused weight prep (all 5 layers) ----
    prep_all<<<235, 256, 0, stream>>>(gw[0], gw[1], gw[2], gw[3], gw[4],
                                      gas[0], gas[1], gas[2], gas[3], gas[4],
                                      gad[0], gad[1], gad[2], gad[3], gad[4],
                                      bt, wesed, wstack);

    // ---- CNN (padded layout; single memset zeroes all borders) ----
    hipMemsetAsync(cfp, 0, (size_t)140 * PSZ * 4, stream);
    pad_input<<<(4 * 4096 + 255) / 256, 256, 0, stream>>>(cf, cfp);
    conv3x3_pad<4><<<dim3(16, 16), 256, 0, stream>>>(cfp, cw[0], cb[0], c1p);
    conv3x3_pad<16><<<dim3(16, 32), 256, 0, stream>>>(c1p, cw[1], cb[1], c2p);
    conv3x3_pad<32><<<dim3(16, 64), 256, 0, stream>>>(c2p, cw[2], cb[2], c3p);
    conv3x3_pad<64><<<dim3(16, 24), 256, 0, stream>>>(c3p, cw[3], cb[3], c4p);
    avgpool_c<<<24, 256, 0, stream>>>(c4p, gfeat);

    // ---- h0 (padded to 48, fp16) + masks ----
    build_h0<<<(N + 255) / 256, 256, 0, stream>>>(x, gfeat, hA16, masks, N);

    // ---- CSR by dst (incl self loops), parallel scan ----
    hipMemsetAsync(cnt, 0, (size_t)N * 4, stream);
    count_dst<<<(EN + 255) / 256, 256, 0, stream>>>(ei, cnt, E, N);
    scan_blocks<<<NB, 256, 0, stream>>>(cnt, pref, bsums, N);
    scan_sums<<<1, 64, 0, stream>>>(bsums, NB);
    scan_apply<<<NB, 256, 0, stream>>>(pref, bsums, indptr, cursor, N, EN);
    scatter_edges<<<(EN + 255) / 256, 256, 0, stream>>>(ei, cursor, col, E, N);

    // ---- GAT layers ----
    const int Hs[5] = {8, 16, 8, 8, 16};
    const int Cs[5] = {64, 128, 256, 128, 2};
    const int Kp[5] = {48, 64, 128, 256, 128};
    const int btOffA[5] = {0, 24576, 155648, 417792, 0};
    const int weOffA[5] = {0, 768, 2816, 4864, 8960};

    const __half* hin16 = hA16;
    __half* hout16[4]  = {hB16, hA16, hB16, hA16};

    for (int lyr = 0; lyr < 5; ++lyr) {
        int KP = Kp[lyr], H = Hs[lyr], C = Cs[lyr];
        int KA = H * KP;
        esed_kernel<<<(N * 2 * H + 255) / 256, 256, 0, stream>>>(hin16, wesed + weOffA[lyr],
                                                                 esed, N, KP, 2 * H);
        attn_kernel<<<(N * H + 255) / 256, 256, 0, stream>>>(esed, indptr, col,
                                                             palpha, zinv, N, H);
        if (lyr == 0)
            gat_gather4<8, 48, 20><<<(N + 19) / 20, 240, 0, stream>>>(
                hin16, palpha, zinv, indptr, col, g, N);
        else if (lyr == 1)
            gat_gather4<16, 64, 16><<<(N + 15) / 16, 256, 0, stream>>>(
                hin16, palpha, zinv, indptr, col, g, N);
        else if (lyr == 2)
            gat_gather4<8, 128, 8><<<(N + 7) / 8, 256, 0, stream>>>(
                hin16, palpha, zinv, indptr, col, g, N);
        else if (lyr == 3)
            gat_gather4<8, 256, 4><<<(N + 3) / 4, 256, 0, stream>>>(
                hin16, palpha, zinv, indptr, col, g, N);
        else
            gat_gather2f<16, 128, 4><<<(N + 3) / 4, 256, 0, stream>>>(
                hin16, palpha, zinv, indptr, col,
                wstack, gb[4], masks, x, (float*)d_out, N);

        if (lyr < 4) {
            const unsigned short* btL = bt + btOffA[lyr];
            int gx = (N + 63) / 64;        // 157
            gemm_lds<<<dim3(gx, C / 64), 256, 0, stream>>>(g, btL, gb[lyr], masks,
                                                           hout16[lyr], N, KA, C);
            hin16 = hout16[lyr];
        }
    }
}

// Round 9
// 528.441 us; speedup vs baseline: 1.0797x; 1.0498x over previous
//
#include <hip/hip_runtime.h>
#include <hip/hip_fp16.h>
#include <math.h>

// ---------------------------------------------------------------------------
// NetGlobGATFix. R25: project-first fused final layer (L4).
//   - L4 had H*C=32 < KP=128, so gather-then-project wasted 4x gather traffic
//     plus a 10.9MB palpha round-trip (gather2f 43.2us + attn ~12us).
//   - Now: wcomb (128x64 = [es|ed|y-proj W4]) built in prep; one esed-width-64
//     pass -> eyp[n][64]; final_attn: 32 lanes/node, lane (h,c) does
//     p=exp(lrelu(es[src,h]+ed[n,h])), acc += p*y[src,h,c], z inline,
//     shfl-reduce over heads, mask epilogue. No palpha/zinv for L4.
//   - es/ed bit-identical to old path; a-sum reassociated (k before e),
//     ~1e-6 rel. Everything else identical to R24 (554.7us).
// ---------------------------------------------------------------------------

#define DEVFN static __device__ __forceinline__

typedef __attribute__((ext_vector_type(8))) _Float16 half8;
typedef __attribute__((ext_vector_type(4))) _Float16 half4v;
typedef __attribute__((ext_vector_type(4))) float f32x4;

DEVFN float selu_f(float v) {
    const float scale = 1.0507009873554805f;
    const float alpha = 1.6732632423543772f;
    return v > 0.f ? scale * v : scale * alpha * (expf(v) - 1.f);
}

DEVFN float lrelu02(float v) { return v > 0.f ? v : 0.2f * v; }

// ---------------- CNN (padded 66x66 layout) ----------------
#define PST 66
#define PSZ (66 * 66)

__global__ void pad_input(const float* __restrict__ cf, float* __restrict__ out) {
    int t = blockIdx.x * blockDim.x + threadIdx.x;
    if (t >= 4 * 4096) return;
    int c = t >> 12, pix = t & 4095;
    int y = pix >> 6, x = pix & 63;
    out[c * PSZ + (y + 1) * PST + (x + 1)] = cf[t];
}

template <int CIN>
__global__ __launch_bounds__(256) void conv3x3_pad(const float* __restrict__ in,
                                                   const float* __restrict__ w,
                                                   const float* __restrict__ b,
                                                   float* __restrict__ out) {
    int x  = threadIdx.x & 63;
    int yg = threadIdx.x >> 6;
    int y  = blockIdx.x * 4 + yg;          // 0..63
    int co = blockIdx.y;
    float acc = b[co];
    const float* wp = w + (size_t)co * CIN * 9;
#pragma unroll 4
    for (int ci = 0; ci < CIN; ++ci) {
        const float* ip = in + ci * PSZ + y * PST + x;
        const float* wr = wp + ci * 9;
        acc += wr[0] * ip[0]           + wr[1] * ip[1]           + wr[2] * ip[2]
             + wr[3] * ip[PST]         + wr[4] * ip[PST + 1]     + wr[5] * ip[PST + 2]
             + wr[6] * ip[2 * PST]     + wr[7] * ip[2 * PST + 1] + wr[8] * ip[2 * PST + 2];
    }
    out[(size_t)co * PSZ + (y + 1) * PST + (x + 1)] = selu_f(acc);
}

__global__ void avgpool_c(const float* __restrict__ in, float* __restrict__ gfeat) {
    int c = blockIdx.x;            // 24 blocks
    int t = threadIdx.x;           // 256 threads
    float s = 0.f;
    for (int i = t; i < 4096; i += 256) {
        int y = i >> 6, x = i & 63;
        s += in[c * PSZ + (y + 1) * PST + (x + 1)];
    }
#pragma unroll
    for (int off = 32; off >= 1; off >>= 1) s += __shfl_xor(s, off);
    __shared__ float red[4];
    int wave = t >> 6, lane = t & 63;
    if (lane == 0) red[wave] = s;
    __syncthreads();
    if (t == 0) gfeat[c] = (red[0] + red[1] + red[2] + red[3]) * (1.f / 4096.f);
}

// ---------------- node feature init (padded to 48 ch, fp16) + masks ---------
__global__ void build_h0(const float* __restrict__ x, const float* __restrict__ gfeat,
                         __half* __restrict__ h0f, unsigned* __restrict__ masks, int N) {
    int n = blockIdx.x * blockDim.x + threadIdx.x;
    if (n >= N) return;
    float x0 = x[n * 10 + 0], x1 = x[n * 10 + 1];
    unsigned mk = (x0 == 1.f ? 1u : 0u) | (x0 == 0.f ? 2u : 0u) |
                  (x1 == 0.f ? 4u : 0u) | (x1 == 1.f ? 8u : 0u);
    masks[n] = mk;
    __half* hq = h0f + (size_t)n * 48;
#pragma unroll
    for (int j = 0; j < 48; ++j) {
        float v = (j < 24) ? gfeat[j] : (j < 34 ? x[n * 10 + (j - 24)] : 0.f);
        hq[j] = __float2half(v);
    }
}

// ---------------- CSR build (parallel scan) ----------------
__global__ void count_dst(const int* __restrict__ ei, int* __restrict__ cnt, int E, int N) {
    int t = blockIdx.x * blockDim.x + threadIdx.x;
    if (t >= E + N) return;
    int dst = (t < E) ? ei[E + t] : (t - E);
    atomicAdd(&cnt[dst], 1);
}

__global__ void scan_blocks(const int* __restrict__ cnt, int* __restrict__ pref,
                            int* __restrict__ bsums, int n) {
    __shared__ int sdata[256];
    int i = blockIdx.x * 256 + threadIdx.x;
    int v = (i < n) ? cnt[i] : 0;
    sdata[threadIdx.x] = v;
    __syncthreads();
    for (int off = 1; off < 256; off <<= 1) {
        int tmp = (threadIdx.x >= off) ? sdata[threadIdx.x - off] : 0;
        __syncthreads();
        sdata[threadIdx.x] += tmp;
        __syncthreads();
    }
    if (i < n) pref[i] = sdata[threadIdx.x] - v;
    if (threadIdx.x == 255) bsums[blockIdx.x] = sdata[255];
}

__global__ void scan_sums(int* __restrict__ bsums, int nb) {
    int tid = threadIdx.x;                 // 64
    int orig = (tid < nb) ? bsums[tid] : 0;
    int v = orig;
#pragma unroll
    for (int off = 1; off < 64; off <<= 1) {
        int u = __shfl_up(v, off);
        if (tid >= off) v += u;
    }
    if (tid < nb) bsums[tid] = v - orig;
}

__global__ void scan_apply(const int* __restrict__ pref, const int* __restrict__ bsums,
                           int* __restrict__ indptr, int* __restrict__ cursor,
                           int n, int total) {
    int i = blockIdx.x * 256 + threadIdx.x;
    if (i == 0) indptr[n] = total;
    if (i >= n) return;
    int e = bsums[blockIdx.x] + pref[i];
    indptr[i] = e;
    cursor[i] = e;
}

__global__ void scatter_edges(const int* __restrict__ ei, int* __restrict__ cursor,
                              int* __restrict__ col, int E, int N) {
    int t = blockIdx.x * blockDim.x + threadIdx.x;
    if (t >= E + N) return;
    int src, dst;
    if (t < E) { src = ei[t]; dst = ei[E + t]; }
    else       { src = dst = t - E; }
    int pos = atomicAdd(&cursor[dst], 1);
    col[pos] = src;
}

// ---------------- fused one-shot weight prep --------------------------------
// bt layout per layer: bt[btOff + m*KA + h*Kp + k] = fp16(W[k*HC + h*C + m])
// wesed[weOff + k*2H + o] = sum_c W[k,h*C+c]*a[h,c]  (h=o%H, a=as/ad by o<H).
// wcomb (layer 4, 128x64): cols 0..31 = es/ed weights, cols 32..63 = W4 cols
//   (y-projection), so eyp = hin @ wcomb gives [es(16)|ed(16)|y(32)] per node.
__global__ __launch_bounds__(256) void prep_all(
        const float* __restrict__ W0, const float* __restrict__ W1,
        const float* __restrict__ W2, const float* __restrict__ W3,
        const float* __restrict__ W4,
        const float* __restrict__ as0, const float* __restrict__ as1,
        const float* __restrict__ as2, const float* __restrict__ as3,
        const float* __restrict__ as4,
        const float* __restrict__ ad0, const float* __restrict__ ad1,
        const float* __restrict__ ad2, const float* __restrict__ ad3,
        const float* __restrict__ ad4,
        unsigned short* __restrict__ bt, float* __restrict__ wesed,
        float* __restrict__ wcomb) {
    const int Kc[5]  = {34, 64, 128, 256, 128};
    const int Kpc[5] = {48, 64, 128, 256, 128};
    const int Hc[5]  = {8, 16, 8, 8, 16};
    const int Cc[5]  = {64, 128, 256, 128, 2};
    const int HCc[5] = {512, 2048, 2048, 1024, 32};
    const int KAc[5] = {384, 1024, 1024, 2048, 2048};
    const int btOff[5] = {0, 24576, 155648, 417792, 679936};
    const int weOff[5] = {0, 768, 2816, 4864, 8960};

    int b = blockIdx.x, tid = threadIdx.x;

    if (b < 168) {
        // ---- LDS-tiled transpose, one (layer, head, 64x64 tile) per block --
        int lyr, tloc;
        if (b < 8)        { lyr = 0; tloc = b; }
        else if (b < 40)  { lyr = 1; tloc = b - 8; }
        else if (b < 104) { lyr = 2; tloc = b - 40; }
        else              { lyr = 3; tloc = b - 104; }
        const int ktl[4] = {1, 1, 2, 4};   // ceil(Kp/64)
        const int mtl[4] = {1, 2, 4, 2};   // ceil(C/64)
        int kt = ktl[lyr], mt = mtl[lyr];
        int per_h = kt * mt;
        int h = tloc / per_h, r = tloc - h * per_h;
        int ki = r % kt, mi = r / kt;
        int k0 = ki * 64, m0 = mi * 64;
        int K = Kc[lyr], Kp = Kpc[lyr], C = Cc[lyr], HC = HCc[lyr], KA = KAc[lyr];
        const float* W;
        if (lyr == 0) W = W0; else if (lyr == 1) W = W1;
        else if (lyr == 2) W = W2; else W = W3;

        __shared__ float tile[64][65];
        int c = tid & 63, rg = tid >> 6;
        for (int r2 = rg; r2 < 64; r2 += 4) {       // coalesced 256B reads
            int k = k0 + r2, m = m0 + c;
            float v = (k < K && m < C) ? W[(size_t)k * HC + h * C + m] : 0.f;
            tile[r2][c] = v;
        }
        __syncthreads();
        unsigned short* bp = bt + btOff[lyr];
        for (int mr = rg; mr < 64; mr += 4) {       // coalesced 128B fp16 writes
            int m = m0 + mr, k = k0 + c;
            if (m < C && k < Kp)
                bp[(size_t)m * KA + h * Kp + k] =
                    __half_as_ushort(__float2half(tile[c][mr]));
        }
    } else if (b < 200) {
        // ---- wcomb for layer 4: 8192 outputs (128 x 64) ----
        int u = (b - 168) * 256 + tid;
        int k = u >> 6, o = u & 63;
        float s;
        if (o < 32) {                       // es/ed weights (same as wesed L4)
            int h = (o < 16) ? o : o - 16;
            const float* av = ((o < 16) ? as4 : ad4) + h * 2;
            s = W4[k * 32 + h * 2 + 0] * av[0] + W4[k * 32 + h * 2 + 1] * av[1];
        } else {                            // y projection: raw W4 column
            s = W4[k * 32 + (o - 32)];
        }
        wcomb[u] = s;
    } else {
        // ---- wesed dots: sizes {768,2048,2048,4096,4096} -> 51 blocks ----
        int wb = b - 200;
        int lyr, u0;
        if (wb < 3)       { lyr = 0; u0 = wb * 256; }
        else if (wb < 11) { lyr = 1; u0 = (wb - 3) * 256; }
        else if (wb < 19) { lyr = 2; u0 = (wb - 11) * 256; }
        else if (wb < 35) { lyr = 3; u0 = (wb - 19) * 256; }
        else              { lyr = 4; u0 = (wb - 35) * 256; }
        int u = u0 + tid;
        int K = Kc[lyr], Kp = Kpc[lyr], H = Hc[lyr], C = Cc[lyr], HC = HCc[lyr];
        int H2 = 2 * H;
        if (u < Kp * H2) {
            int k = u / H2, o = u - k * H2;
            float s = 0.f;
            if (k < K) {
                int h = (o < H) ? o : o - H;
                const float *W, *as_, *ad_;
                if (lyr == 0)      { W = W0; as_ = as0; ad_ = ad0; }
                else if (lyr == 1) { W = W1; as_ = as1; ad_ = ad1; }
                else if (lyr == 2) { W = W2; as_ = as2; ad_ = ad2; }
                else if (lyr == 3) { W = W3; as_ = as3; ad_ = ad3; }
                else               { W = W4; as_ = as4; ad_ = ad4; }
                const float* av = ((o < H) ? as_ : ad_) + h * C;
                const float* wp = W + (size_t)k * HC + h * C;
#pragma unroll 4
                for (int c2 = 0; c2 < C; ++c2) s += wp[c2] * av[c2];
            }
            wesed[weOff[lyr] + u] = s;
        }
    }
}

// ---------------- es/ed (and eyp): out[n,o] = hin16[n,:] @ w[:,o] -----------
__global__ void esed_kernel(const __half* __restrict__ hin, const float* __restrict__ wesed,
                            float* __restrict__ esed, int N, int Kp, int H2) {
    int t = blockIdx.x * blockDim.x + threadIdx.x;
    if (t >= N * H2) return;
    int n = t / H2, o = t - n * H2;
    const __half2* hp = (const __half2*)(hin + (size_t)n * Kp);
    float s = 0.f;
    for (int k2 = 0; k2 < Kp / 2; ++k2) {
        float2 f = __half22float2(hp[k2]);
        s += f.x * wesed[(2 * k2) * H2 + o] + f.y * wesed[(2 * k2 + 1) * H2 + o];
    }
    esed[t] = s;
}

// -------- attention (layers 0-3): single pass, 4-deep -----------------------
__global__ void attn_kernel(const float* __restrict__ esed,
                            const int* __restrict__ indptr, const int* __restrict__ col,
                            float* __restrict__ palpha, float* __restrict__ zinv,
                            int N, int H) {
    int t = blockIdx.x * blockDim.x + threadIdx.x;
    if (t >= N * H) return;
    int n = t / H, h = t - n * H;
    int H2 = 2 * H;
    float edv = esed[n * H2 + H + h];
    int beg = indptr[n], end = indptr[n + 1];
    float z = 0.f;
    int i = beg;
    for (; i + 3 < end; i += 4) {
        int s0 = col[i], s1 = col[i + 1], s2 = col[i + 2], s3 = col[i + 3];
        float e0 = esed[s0 * H2 + h];
        float e1 = esed[s1 * H2 + h];
        float e2 = esed[s2 * H2 + h];
        float e3 = esed[s3 * H2 + h];
        float p0 = expf(lrelu02(e0 + edv));
        float p1 = expf(lrelu02(e1 + edv));
        float p2 = expf(lrelu02(e2 + edv));
        float p3 = expf(lrelu02(e3 + edv));
        palpha[(size_t)(i + 0) * H + h] = p0;
        palpha[(size_t)(i + 1) * H + h] = p1;
        palpha[(size_t)(i + 2) * H + h] = p2;
        palpha[(size_t)(i + 3) * H + h] = p3;
        z += p0; z += p1; z += p2; z += p3;
    }
    for (; i < end; ++i) {
        float e = lrelu02(esed[col[i] * H2 + h] + edv);
        float p = expf(e);
        palpha[(size_t)i * H + h] = p;
        z += p;
    }
    zinv[t] = (1.f / H) / (z + 1e-16f);
}

// -------- gather: half4 (8B) loads, 4-deep ----------------------------------
template <int H, int KP, int NPB>
__global__ __launch_bounds__(NPB * KP / 4) void gat_gather4(
        const __half* __restrict__ hinf, const float* __restrict__ palpha,
        const float* __restrict__ zinv, const int* __restrict__ indptr,
        const int* __restrict__ col, __half* __restrict__ g, int N) {
    const int TPN = KP / 4;
    int sub = threadIdx.x / TPN;
    int j   = threadIdx.x % TPN;
    int n = blockIdx.x * NPB + sub;
    if (n >= N) return;
    int c0 = j * 4;
    float acc[H][4];
#pragma unroll
    for (int h = 0; h < H; ++h)
#pragma unroll
        for (int t = 0; t < 4; ++t) acc[h][t] = 0.f;

    int beg = indptr[n], end = indptr[n + 1];
    int i = beg;
    for (; i + 3 < end; i += 4) {
        int s0 = col[i], s1 = col[i + 1], s2 = col[i + 2], s3 = col[i + 3];
        half4v hv0 = *(const half4v*)(hinf + (size_t)s0 * KP + c0);
        half4v hv1 = *(const half4v*)(hinf + (size_t)s1 * KP + c0);
        half4v hv2 = *(const half4v*)(hinf + (size_t)s2 * KP + c0);
        half4v hv3 = *(const half4v*)(hinf + (size_t)s3 * KP + c0);
#pragma unroll
        for (int e = 0; e < 4; ++e) {
            half4v hv = (e == 0) ? hv0 : (e == 1) ? hv1 : (e == 2) ? hv2 : hv3;
            float f[4] = {(float)hv[0], (float)hv[1], (float)hv[2], (float)hv[3]};
            const float2* ap = (const float2*)(palpha + (size_t)(i + e) * H);
#pragma unroll
            for (int h2 = 0; h2 < H / 2; ++h2) {
                float2 aa = ap[h2];
#pragma unroll
                for (int t = 0; t < 4; ++t) {
                    acc[2 * h2 + 0][t] += aa.x * f[t];
                    acc[2 * h2 + 1][t] += aa.y * f[t];
                }
            }
        }
    }
    for (; i < end; ++i) {
        int src = col[i];
        half4v hv = *(const half4v*)(hinf + (size_t)src * KP + c0);
        float f[4] = {(float)hv[0], (float)hv[1], (float)hv[2], (float)hv[3]};
        const float2* ap = (const float2*)(palpha + (size_t)i * H);
#pragma unroll
        for (int h2 = 0; h2 < H / 2; ++h2) {
            float2 aa = ap[h2];
#pragma unroll
            for (int t = 0; t < 4; ++t) {
                acc[2 * h2 + 0][t] += aa.x * f[t];
                acc[2 * h2 + 1][t] += aa.y * f[t];
            }
        }
    }

    __half* gp = g + (size_t)n * (H * KP) + c0;
#pragma unroll
    for (int h = 0; h < H; ++h) {
        float zf = zinv[n * H + h];
        __half2 lo = __floats2half2_rn(acc[h][0] * zf, acc[h][1] * zf);
        __half2 hi = __floats2half2_rn(acc[h][2] * zf, acc[h][3] * zf);
        union { __half2 h2[2]; float2 f2; } u;
        u.h2[0] = lo; u.h2[1] = hi;
        *(float2*)(gp + h * KP) = u.f2;
    }
}

// -------- layer 4: fused attention + projected gather + output --------------
// eyp[n][64] = [es(16) | ed(16) | y(h,c) (32)]. 32 lanes/node; lane j=(h,c)
// with h=j>>1, c=j&1: p = exp(lrelu(es[src,h]+ed[n,h])), acc += p*y[src,h,c],
// z accumulated inline (per-h identical in both c lanes). Reduce over heads
// by shfl_xor strides 2..16, swap parities, mask epilogue.
template <int NPB>
__global__ __launch_bounds__(NPB * 32) void final_attn(
        const float* __restrict__ eyp, const int* __restrict__ indptr,
        const int* __restrict__ col, const float* __restrict__ b5,
        const unsigned* __restrict__ masks, const float* __restrict__ x,
        float* __restrict__ outp, int N) {
    int sub = threadIdx.x >> 5;
    int j   = threadIdx.x & 31;
    int n = blockIdx.x * NPB + sub;
    if (n >= N) return;
    int h = j >> 1;
    float edv = eyp[(size_t)n * 64 + 16 + h];
    int beg = indptr[n], end = indptr[n + 1];
    float z = 0.f, a = 0.f;
    int i = beg;
    for (; i + 1 < end; i += 2) {
        int s0 = col[i], s1 = col[i + 1];
        const float* r0 = eyp + (size_t)s0 * 64;
        const float* r1 = eyp + (size_t)s1 * 64;
        float es0 = r0[h], y0 = r0[32 + j];
        float es1 = r1[h], y1 = r1[32 + j];
        float p0 = expf(lrelu02(es0 + edv));
        float p1 = expf(lrelu02(es1 + edv));
        z += p0; a += p0 * y0;
        z += p1; a += p1 * y1;
    }
    for (; i < end; ++i) {
        const float* r = eyp + (size_t)col[i] * 64;
        float p = expf(lrelu02(r[h] + edv));
        z += p; a += p * r[32 + j];
    }
    float zf = (1.f / 16.f) / (z + 1e-16f);
    float val = a * zf;
#pragma unroll
    for (int off = 2; off <= 16; off <<= 1) val += __shfl_xor(val, off, 32);
    float other = __shfl_xor(val, 1, 32);        // opposite parity's sum
    if (j == 0) {
        unsigned mk = masks[n];
        float v0 = x[n * 10 + 0] + selu_f(val + b5[0]);
        float v1 = x[n * 10 + 1] + selu_f(other + b5[1]);
        if (mk & 2u) v0 = 0.f; else if (mk & 1u) v0 = 1.f;
        if (mk & 8u) v1 = 1.f; else if (mk & 4u) v1 = 0.f;
        outp[n * 2 + 0] = v0;
        outp[n * 2 + 1] = v1;
    }
}

// ---------------- LDS-staged f16 MFMA GEMM (64x64 tile, BK=64) --------------
#define LDP 72
__global__ __launch_bounds__(256) void gemm_lds(const __half* __restrict__ A,
                                                const unsigned short* __restrict__ Bhi,
                                                const float* __restrict__ bias,
                                                const unsigned* __restrict__ masks,
                                                __half* __restrict__ O16,
                                                int N, int K, int M) {
    __shared__ __half lA[64 * LDP], lB[64 * LDP];
    int tid = threadIdx.x;
    int wave = tid >> 6, lane = tid & 63;
    int ln16 = lane & 15, q = lane >> 4;
    int row0 = blockIdx.x * 64;
    int col0 = blockIdx.y * 64;

    int r0 = tid >> 3, r1 = r0 + 32;
    int ac = (tid & 7) * 8;                      // col offset in halves
    int ga0 = min(row0 + r0, N - 1);
    int ga1 = min(row0 + r1, N - 1);
    const __half* Bp = (const __half*)Bhi;
    const __half* a0p = A + (size_t)ga0 * K + ac;
    const __half* a1p = A + (size_t)ga1 * K + ac;
    const __half* b0p = Bp + (size_t)(col0 + r0) * K + ac;
    const __half* b1p = Bp + (size_t)(col0 + r1) * K + ac;

    half8 ra0 = *(const half8*)(a0p);
    half8 ra1 = *(const half8*)(a1p);
    half8 rb0 = *(const half8*)(b0p);
    half8 rb1 = *(const half8*)(b1p);

    f32x4 acc[4];
#pragma unroll
    for (int j = 0; j < 4; ++j) acc[j] = (f32x4){0.f, 0.f, 0.f, 0.f};

    for (int kc = 0; kc < K; kc += 64) {
        __syncthreads();
        *(half8*)(lA + r0 * LDP + ac) = ra0;
        *(half8*)(lA + r1 * LDP + ac) = ra1;
        *(half8*)(lB + r0 * LDP + ac) = rb0;
        *(half8*)(lB + r1 * LDP + ac) = rb1;
        __syncthreads();
        int kn = kc + 64;
        if (kn < K) {
            ra0 = *(const half8*)(a0p + kn);
            ra1 = *(const half8*)(a1p + kn);
            rb0 = *(const half8*)(b0p + kn);
            rb1 = *(const half8*)(b1p + kn);
        }
#pragma unroll
        for (int kk = 0; kk < 2; ++kk) {
            half8 af = *(const half8*)(lA + (wave * 16 + ln16) * LDP + kk * 32 + q * 8);
#pragma unroll
            for (int j = 0; j < 4; ++j) {
                half8 bf = *(const half8*)(lB + (j * 16 + ln16) * LDP + kk * 32 + q * 8);
                acc[j] = __builtin_amdgcn_mfma_f32_16x16x32_f16(af, bf, acc[j], 0, 0, 0);
            }
        }
    }

#pragma unroll
    for (int j = 0; j < 4; ++j) {
        int cc = col0 + j * 16 + ln16;
        float bv = bias[cc];
#pragma unroll
        for (int r = 0; r < 4; ++r) {
            int rr = row0 + wave * 16 + q * 4 + r;
            if (rr >= N) continue;
            float v = selu_f(acc[j][r] + bv);
            if (cc < 2) {
                unsigned mk = masks[rr];
                if (cc == 0) { if (mk & 2u) v = 0.f; else if (mk & 1u) v = 1.f; }
                else         { if (mk & 8u) v = 1.f; else if (mk & 4u) v = 0.f; }
            }
            O16[(size_t)rr * M + cc] = __float2half(v);
        }
    }
}

// ---------------------------------------------------------------------------
extern "C" void kernel_launch(void* const* d_in, const int* in_sizes, int n_in,
                              void* d_out, int out_size, void* d_ws, size_t ws_size,
                              hipStream_t stream) {
    const float* x   = (const float*)d_in[0];
    const int*   ei  = (const int*)d_in[1];
    const float* cf  = (const float*)d_in[2];
    const float* cw[4] = {(const float*)d_in[3], (const float*)d_in[5],
                          (const float*)d_in[7], (const float*)d_in[9]};
    const float* cb[4] = {(const float*)d_in[4], (const float*)d_in[6],
                          (const float*)d_in[8], (const float*)d_in[10]};
    const float* gw[5], *gas[5], *gad[5], *gb[5];
    for (int i = 0; i < 5; ++i) {
        gw[i]  = (const float*)d_in[11 + 4 * i];
        gas[i] = (const float*)d_in[12 + 4 * i];
        gad[i] = (const float*)d_in[13 + 4 * i];
        gb[i]  = (const float*)d_in[14 + 4 * i];
    }
    const int N = in_sizes[0] / 10;        // 10000
    const int E = in_sizes[1] / 2;         // 160000
    const int EN = E + N;
    const int NB = (N + 255) / 256;        // scan blocks (40)

    // ---- workspace carve-up ----
    char* base = (char*)d_ws;
    size_t off = 0;
    auto alloc = [&](size_t bytes) -> char* {
        char* p = base + off;
        off = (off + bytes + 255) & ~(size_t)255;
        return p;
    };
    float* cfp   = (float*)alloc((size_t)4 * PSZ * 4);
    float* c1p   = (float*)alloc((size_t)16 * PSZ * 4);
    float* c2p   = (float*)alloc((size_t)32 * PSZ * 4);
    float* c3p   = (float*)alloc((size_t)64 * PSZ * 4);
    float* c4p   = (float*)alloc((size_t)24 * PSZ * 4);
    float* gfeat = (float*)alloc(24 * 4);
    __half* hA16 = (__half*)alloc((size_t)N * 256 * 2);
    __half* hB16 = (__half*)alloc((size_t)N * 256 * 2);
    __half* g    = (__half*)alloc((size_t)N * 2048 * 2);
    float* esed  = (float*)alloc((size_t)N * 32 * 4);
    float* eyp   = (float*)alloc((size_t)N * 64 * 4);        // L4 [es|ed|y]
    float* zinv  = (float*)alloc((size_t)N * 16 * 4);
    float* palpha = (float*)alloc((size_t)EN * 16 * 4);      // fp32 numerators
    float* wesed = (float*)alloc((size_t)13056 * 4);         // layers 0-3 (+L4 unused)
    float* wcomb = (float*)alloc((size_t)8192 * 4);          // L4 combined weights
    unsigned short* bt = (unsigned short*)alloc((size_t)679936 * 2);  // 4 GEMM layers
    unsigned* masks = (unsigned*)alloc((size_t)N * 4);
    int* cnt    = (int*)alloc((size_t)N * 4);
    int* pref   = (int*)alloc((size_t)N * 4);
    int* bsums  = (int*)alloc(64 * 4);
    int* indptr = (int*)alloc((size_t)(N + 1) * 4);
    int* cursor = (int*)alloc((size_t)N * 4);
    int* col    = (int*)alloc((size_t)EN * 4);
    (void)ws_size; // ~78 MB

    // ---- one-shot fused weight prep (all 5 layers) ----
    prep_all<<<251, 256, 0, stream>>>(gw[0], gw[1], gw[2], gw[3], gw[4],
                                      gas[0], gas[1], gas[2], gas[3], gas[4],
                                      gad[0], gad[1], gad[2], gad[3], gad[4],
                                      bt, wesed, wcomb);

    // ---- CNN (padded layout; single memset zeroes all borders) ----
    hipMemsetAsync(cfp, 0, (size_t)140 * PSZ * 4, stream);
    pad_input<<<(4 * 4096 + 255) / 256, 256, 0, stream>>>(cf, cfp);
    conv3x3_pad<4><<<dim3(16, 16), 256, 0, stream>>>(cfp, cw[0], cb[0], c1p);
    conv3x3_pad<16><<<dim3(16, 32), 256, 0, stream>>>(c1p, cw[1], cb[1], c2p);
    conv3x3_pad<32><<<dim3(16, 64), 256, 0, stream>>>(c2p, cw[2], cb[2], c3p);
    conv3x3_pad<64><<<dim3(16, 24), 256, 0, stream>>>(c3p, cw[3], cb[3], c4p);
    avgpool_c<<<24, 256, 0, stream>>>(c4p, gfeat);

    // ---- h0 (padded to 48, fp16) + masks ----
    build_h0<<<(N + 255) / 256, 256, 0, stream>>>(x, gfeat, hA16, masks, N);

    // ---- CSR by dst (incl self loops), parallel scan ----
    hipMemsetAsync(cnt, 0, (size_t)N * 4, stream);
    count_dst<<<(EN + 255) / 256, 256, 0, stream>>>(ei, cnt, E, N);
    scan_blocks<<<NB, 256, 0, stream>>>(cnt, pref, bsums, N);
    scan_sums<<<1, 64, 0, stream>>>(bsums, NB);
    scan_apply<<<NB, 256, 0, stream>>>(pref, bsums, indptr, cursor, N, EN);
    scatter_edges<<<(EN + 255) / 256, 256, 0, stream>>>(ei, cursor, col, E, N);

    // ---- GAT layers ----
    const int Hs[5] = {8, 16, 8, 8, 16};
    const int Cs[5] = {64, 128, 256, 128, 2};
    const int Kp[5] = {48, 64, 128, 256, 128};
    const int btOffA[5] = {0, 24576, 155648, 417792, 0};
    const int weOffA[5] = {0, 768, 2816, 4864, 8960};

    const __half* hin16 = hA16;
    __half* hout16[4]  = {hB16, hA16, hB16, hA16};

    for (int lyr = 0; lyr < 5; ++lyr) {
        int KP = Kp[lyr], H = Hs[lyr], C = Cs[lyr];
        int KA = H * KP;
        if (lyr == 4) {
            // project-first fused final layer
            esed_kernel<<<(N * 64 + 255) / 256, 256, 0, stream>>>(hin16, wcomb, eyp,
                                                                  N, 128, 64);
            final_attn<8><<<(N + 7) / 8, 256, 0, stream>>>(eyp, indptr, col, gb[4],
                                                           masks, x, (float*)d_out, N);
            break;
        }
        esed_kernel<<<(N * 2 * H + 255) / 256, 256, 0, stream>>>(hin16, wesed + weOffA[lyr],
                                                                 esed, N, KP, 2 * H);
        attn_kernel<<<(N * H + 255) / 256, 256, 0, stream>>>(esed, indptr, col,
                                                             palpha, zinv, N, H);
        if (lyr == 0)
            gat_gather4<8, 48, 20><<<(N + 19) / 20, 240, 0, stream>>>(
                hin16, palpha, zinv, indptr, col, g, N);
        else if (lyr == 1)
            gat_gather4<16, 64, 16><<<(N + 15) / 16, 256, 0, stream>>>(
                hin16, palpha, zinv, indptr, col, g, N);
        else if (lyr == 2)
            gat_gather4<8, 128, 8><<<(N + 7) / 8, 256, 0, stream>>>(
                hin16, palpha, zinv, indptr, col, g, N);
        else
            gat_gather4<8, 256, 4><<<(N + 3) / 4, 256, 0, stream>>>(
                hin16, palpha, zinv, indptr, col, g, N);

        const unsigned short* btL = bt + btOffA[lyr];
        int gx = (N + 63) / 64;        // 157
        gemm_lds<<<dim3(gx, C / 64), 256, 0, stream>>>(g, btL, gb[lyr], masks,
                                                       hout16[lyr], N, KA, C);
        hin16 = hout16[lyr];
    }
}

// Round 10
// 509.359 us; speedup vs baseline: 1.1202x; 1.0375x over previous
//
#include <hip/hip_runtime.h>
#include <hip/hip_fp16.h>
#include <math.h>

// ---------------------------------------------------------------------------
// NetGlobGATFix. R26: attn fused into gather via LDS broadcast (L1-L3).
//   - R23's shfl-broadcast fusion failed (H serial shfl/edge -> VALU-bound).
//     New mechanism: phase A computes the chunk's ECxH p-values (1 exp/lane,
//     R23's proven lane->(e,h) map) into a per-node LDS strip; phase B is the
//     UNCHANGED pipelined gather loop with alphas as broadcast float4
//     ds_reads. Wave-synchronous (DS in-order per wave + wave_barrier), node
//     groups never cross waves. z class-reduced by shfl_xor (R23-verified).
//   - Kills 3 attn dispatches + ~30MB palpha round-trip. L0 (TPN=12) keeps
//     attn+palpha path; L4 keeps R25's project-first final_attn.
//   - Everything else identical to R25 (528.4us).
// ---------------------------------------------------------------------------

#define DEVFN static __device__ __forceinline__

typedef __attribute__((ext_vector_type(8))) _Float16 half8;
typedef __attribute__((ext_vector_type(4))) _Float16 half4v;
typedef __attribute__((ext_vector_type(4))) float f32x4;

DEVFN float selu_f(float v) {
    const float scale = 1.0507009873554805f;
    const float alpha = 1.6732632423543772f;
    return v > 0.f ? scale * v : scale * alpha * (expf(v) - 1.f);
}

DEVFN float lrelu02(float v) { return v > 0.f ? v : 0.2f * v; }

// ---------------- CNN (padded 66x66 layout) ----------------
#define PST 66
#define PSZ (66 * 66)

__global__ void pad_input(const float* __restrict__ cf, float* __restrict__ out) {
    int t = blockIdx.x * blockDim.x + threadIdx.x;
    if (t >= 4 * 4096) return;
    int c = t >> 12, pix = t & 4095;
    int y = pix >> 6, x = pix & 63;
    out[c * PSZ + (y + 1) * PST + (x + 1)] = cf[t];
}

template <int CIN>
__global__ __launch_bounds__(256) void conv3x3_pad(const float* __restrict__ in,
                                                   const float* __restrict__ w,
                                                   const float* __restrict__ b,
                                                   float* __restrict__ out) {
    int x  = threadIdx.x & 63;
    int yg = threadIdx.x >> 6;
    int y  = blockIdx.x * 4 + yg;          // 0..63
    int co = blockIdx.y;
    float acc = b[co];
    const float* wp = w + (size_t)co * CIN * 9;
#pragma unroll 4
    for (int ci = 0; ci < CIN; ++ci) {
        const float* ip = in + ci * PSZ + y * PST + x;
        const float* wr = wp + ci * 9;
        acc += wr[0] * ip[0]           + wr[1] * ip[1]           + wr[2] * ip[2]
             + wr[3] * ip[PST]         + wr[4] * ip[PST + 1]     + wr[5] * ip[PST + 2]
             + wr[6] * ip[2 * PST]     + wr[7] * ip[2 * PST + 1] + wr[8] * ip[2 * PST + 2];
    }
    out[(size_t)co * PSZ + (y + 1) * PST + (x + 1)] = selu_f(acc);
}

__global__ void avgpool_c(const float* __restrict__ in, float* __restrict__ gfeat) {
    int c = blockIdx.x;            // 24 blocks
    int t = threadIdx.x;           // 256 threads
    float s = 0.f;
    for (int i = t; i < 4096; i += 256) {
        int y = i >> 6, x = i & 63;
        s += in[c * PSZ + (y + 1) * PST + (x + 1)];
    }
#pragma unroll
    for (int off = 32; off >= 1; off >>= 1) s += __shfl_xor(s, off);
    __shared__ float red[4];
    int wave = t >> 6, lane = t & 63;
    if (lane == 0) red[wave] = s;
    __syncthreads();
    if (t == 0) gfeat[c] = (red[0] + red[1] + red[2] + red[3]) * (1.f / 4096.f);
}

// ---------------- node feature init (padded to 48 ch, fp16) + masks ---------
__global__ void build_h0(const float* __restrict__ x, const float* __restrict__ gfeat,
                         __half* __restrict__ h0f, unsigned* __restrict__ masks, int N) {
    int n = blockIdx.x * blockDim.x + threadIdx.x;
    if (n >= N) return;
    float x0 = x[n * 10 + 0], x1 = x[n * 10 + 1];
    unsigned mk = (x0 == 1.f ? 1u : 0u) | (x0 == 0.f ? 2u : 0u) |
                  (x1 == 0.f ? 4u : 0u) | (x1 == 1.f ? 8u : 0u);
    masks[n] = mk;
    __half* hq = h0f + (size_t)n * 48;
#pragma unroll
    for (int j = 0; j < 48; ++j) {
        float v = (j < 24) ? gfeat[j] : (j < 34 ? x[n * 10 + (j - 24)] : 0.f);
        hq[j] = __float2half(v);
    }
}

// ---------------- CSR build (parallel scan) ----------------
__global__ void count_dst(const int* __restrict__ ei, int* __restrict__ cnt, int E, int N) {
    int t = blockIdx.x * blockDim.x + threadIdx.x;
    if (t >= E + N) return;
    int dst = (t < E) ? ei[E + t] : (t - E);
    atomicAdd(&cnt[dst], 1);
}

__global__ void scan_blocks(const int* __restrict__ cnt, int* __restrict__ pref,
                            int* __restrict__ bsums, int n) {
    __shared__ int sdata[256];
    int i = blockIdx.x * 256 + threadIdx.x;
    int v = (i < n) ? cnt[i] : 0;
    sdata[threadIdx.x] = v;
    __syncthreads();
    for (int off = 1; off < 256; off <<= 1) {
        int tmp = (threadIdx.x >= off) ? sdata[threadIdx.x - off] : 0;
        __syncthreads();
        sdata[threadIdx.x] += tmp;
        __syncthreads();
    }
    if (i < n) pref[i] = sdata[threadIdx.x] - v;
    if (threadIdx.x == 255) bsums[blockIdx.x] = sdata[255];
}

__global__ void scan_sums(int* __restrict__ bsums, int nb) {
    int tid = threadIdx.x;                 // 64
    int orig = (tid < nb) ? bsums[tid] : 0;
    int v = orig;
#pragma unroll
    for (int off = 1; off < 64; off <<= 1) {
        int u = __shfl_up(v, off);
        if (tid >= off) v += u;
    }
    if (tid < nb) bsums[tid] = v - orig;
}

__global__ void scan_apply(const int* __restrict__ pref, const int* __restrict__ bsums,
                           int* __restrict__ indptr, int* __restrict__ cursor,
                           int n, int total) {
    int i = blockIdx.x * 256 + threadIdx.x;
    if (i == 0) indptr[n] = total;
    if (i >= n) return;
    int e = bsums[blockIdx.x] + pref[i];
    indptr[i] = e;
    cursor[i] = e;
}

__global__ void scatter_edges(const int* __restrict__ ei, int* __restrict__ cursor,
                              int* __restrict__ col, int E, int N) {
    int t = blockIdx.x * blockDim.x + threadIdx.x;
    if (t >= E + N) return;
    int src, dst;
    if (t < E) { src = ei[t]; dst = ei[E + t]; }
    else       { src = dst = t - E; }
    int pos = atomicAdd(&cursor[dst], 1);
    col[pos] = src;
}

// ---------------- fused one-shot weight prep --------------------------------
// bt layout per layer: bt[btOff + m*KA + h*Kp + k] = fp16(W[k*HC + h*C + m])
// wesed[weOff + k*2H + o] = sum_c W[k,h*C+c]*a[h,c]  (h=o%H, a=as/ad by o<H).
// wcomb (layer 4, 128x64): cols 0..31 = es/ed weights, cols 32..63 = W4 cols.
__global__ __launch_bounds__(256) void prep_all(
        const float* __restrict__ W0, const float* __restrict__ W1,
        const float* __restrict__ W2, const float* __restrict__ W3,
        const float* __restrict__ W4,
        const float* __restrict__ as0, const float* __restrict__ as1,
        const float* __restrict__ as2, const float* __restrict__ as3,
        const float* __restrict__ as4,
        const float* __restrict__ ad0, const float* __restrict__ ad1,
        const float* __restrict__ ad2, const float* __restrict__ ad3,
        const float* __restrict__ ad4,
        unsigned short* __restrict__ bt, float* __restrict__ wesed,
        float* __restrict__ wcomb) {
    const int Kc[5]  = {34, 64, 128, 256, 128};
    const int Kpc[5] = {48, 64, 128, 256, 128};
    const int Hc[5]  = {8, 16, 8, 8, 16};
    const int Cc[5]  = {64, 128, 256, 128, 2};
    const int HCc[5] = {512, 2048, 2048, 1024, 32};
    const int KAc[5] = {384, 1024, 1024, 2048, 2048};
    const int btOff[5] = {0, 24576, 155648, 417792, 679936};
    const int weOff[5] = {0, 768, 2816, 4864, 8960};

    int b = blockIdx.x, tid = threadIdx.x;

    if (b < 168) {
        // ---- LDS-tiled transpose, one (layer, head, 64x64 tile) per block --
        int lyr, tloc;
        if (b < 8)        { lyr = 0; tloc = b; }
        else if (b < 40)  { lyr = 1; tloc = b - 8; }
        else if (b < 104) { lyr = 2; tloc = b - 40; }
        else              { lyr = 3; tloc = b - 104; }
        const int ktl[4] = {1, 1, 2, 4};   // ceil(Kp/64)
        const int mtl[4] = {1, 2, 4, 2};   // ceil(C/64)
        int kt = ktl[lyr], mt = mtl[lyr];
        int per_h = kt * mt;
        int h = tloc / per_h, r = tloc - h * per_h;
        int ki = r % kt, mi = r / kt;
        int k0 = ki * 64, m0 = mi * 64;
        int K = Kc[lyr], Kp = Kpc[lyr], C = Cc[lyr], HC = HCc[lyr], KA = KAc[lyr];
        const float* W;
        if (lyr == 0) W = W0; else if (lyr == 1) W = W1;
        else if (lyr == 2) W = W2; else W = W3;

        __shared__ float tile[64][65];
        int c = tid & 63, rg = tid >> 6;
        for (int r2 = rg; r2 < 64; r2 += 4) {       // coalesced 256B reads
            int k = k0 + r2, m = m0 + c;
            float v = (k < K && m < C) ? W[(size_t)k * HC + h * C + m] : 0.f;
            tile[r2][c] = v;
        }
        __syncthreads();
        unsigned short* bp = bt + btOff[lyr];
        for (int mr = rg; mr < 64; mr += 4) {       // coalesced 128B fp16 writes
            int m = m0 + mr, k = k0 + c;
            if (m < C && k < Kp)
                bp[(size_t)m * KA + h * Kp + k] =
                    __half_as_ushort(__float2half(tile[c][mr]));
        }
    } else if (b < 200) {
        // ---- wcomb for layer 4: 8192 outputs (128 x 64) ----
        int u = (b - 168) * 256 + tid;
        int k = u >> 6, o = u & 63;
        float s;
        if (o < 32) {                       // es/ed weights (same as wesed L4)
            int h = (o < 16) ? o : o - 16;
            const float* av = ((o < 16) ? as4 : ad4) + h * 2;
            s = W4[k * 32 + h * 2 + 0] * av[0] + W4[k * 32 + h * 2 + 1] * av[1];
        } else {                            // y projection: raw W4 column
            s = W4[k * 32 + (o - 32)];
        }
        wcomb[u] = s;
    } else {
        // ---- wesed dots: sizes {768,2048,2048,4096,4096} -> 51 blocks ----
        int wb = b - 200;
        int lyr, u0;
        if (wb < 3)       { lyr = 0; u0 = wb * 256; }
        else if (wb < 11) { lyr = 1; u0 = (wb - 3) * 256; }
        else if (wb < 19) { lyr = 2; u0 = (wb - 11) * 256; }
        else if (wb < 35) { lyr = 3; u0 = (wb - 19) * 256; }
        else              { lyr = 4; u0 = (wb - 35) * 256; }
        int u = u0 + tid;
        int K = Kc[lyr], Kp = Kpc[lyr], H = Hc[lyr], C = Cc[lyr], HC = HCc[lyr];
        int H2 = 2 * H;
        if (u < Kp * H2) {
            int k = u / H2, o = u - k * H2;
            float s = 0.f;
            if (k < K) {
                int h = (o < H) ? o : o - H;
                const float *W, *as_, *ad_;
                if (lyr == 0)      { W = W0; as_ = as0; ad_ = ad0; }
                else if (lyr == 1) { W = W1; as_ = as1; ad_ = ad1; }
                else if (lyr == 2) { W = W2; as_ = as2; ad_ = ad2; }
                else if (lyr == 3) { W = W3; as_ = as3; ad_ = ad3; }
                else               { W = W4; as_ = as4; ad_ = ad4; }
                const float* av = ((o < H) ? as_ : ad_) + h * C;
                const float* wp = W + (size_t)k * HC + h * C;
#pragma unroll 4
                for (int c2 = 0; c2 < C; ++c2) s += wp[c2] * av[c2];
            }
            wesed[weOff[lyr] + u] = s;
        }
    }
}

// ---------------- es/ed (and eyp): out[n,o] = hin16[n,:] @ w[:,o] -----------
__global__ void esed_kernel(const __half* __restrict__ hin, const float* __restrict__ wesed,
                            float* __restrict__ esed, int N, int Kp, int H2) {
    int t = blockIdx.x * blockDim.x + threadIdx.x;
    if (t >= N * H2) return;
    int n = t / H2, o = t - n * H2;
    const __half2* hp = (const __half2*)(hin + (size_t)n * Kp);
    float s = 0.f;
    for (int k2 = 0; k2 < Kp / 2; ++k2) {
        float2 f = __half22float2(hp[k2]);
        s += f.x * wesed[(2 * k2) * H2 + o] + f.y * wesed[(2 * k2 + 1) * H2 + o];
    }
    esed[t] = s;
}

// -------- attention (layer 0 only): single pass, 4-deep ---------------------
__global__ void attn_kernel(const float* __restrict__ esed,
                            const int* __restrict__ indptr, const int* __restrict__ col,
                            float* __restrict__ palpha, float* __restrict__ zinv,
                            int N, int H) {
    int t = blockIdx.x * blockDim.x + threadIdx.x;
    if (t >= N * H) return;
    int n = t / H, h = t - n * H;
    int H2 = 2 * H;
    float edv = esed[n * H2 + H + h];
    int beg = indptr[n], end = indptr[n + 1];
    float z = 0.f;
    int i = beg;
    for (; i + 3 < end; i += 4) {
        int s0 = col[i], s1 = col[i + 1], s2 = col[i + 2], s3 = col[i + 3];
        float e0 = esed[s0 * H2 + h];
        float e1 = esed[s1 * H2 + h];
        float e2 = esed[s2 * H2 + h];
        float e3 = esed[s3 * H2 + h];
        float p0 = expf(lrelu02(e0 + edv));
        float p1 = expf(lrelu02(e1 + edv));
        float p2 = expf(lrelu02(e2 + edv));
        float p3 = expf(lrelu02(e3 + edv));
        palpha[(size_t)(i + 0) * H + h] = p0;
        palpha[(size_t)(i + 1) * H + h] = p1;
        palpha[(size_t)(i + 2) * H + h] = p2;
        palpha[(size_t)(i + 3) * H + h] = p3;
        z += p0; z += p1; z += p2; z += p3;
    }
    for (; i < end; ++i) {
        float e = lrelu02(esed[col[i] * H2 + h] + edv);
        float p = expf(e);
        palpha[(size_t)i * H + h] = p;
        z += p;
    }
    zinv[t] = (1.f / H) / (z + 1e-16f);
}

// -------- gather: half4 (8B) loads, 4-deep (layer 0, palpha path) -----------
template <int H, int KP, int NPB>
__global__ __launch_bounds__(NPB * KP / 4) void gat_gather4(
        const __half* __restrict__ hinf, const float* __restrict__ palpha,
        const float* __restrict__ zinv, const int* __restrict__ indptr,
        const int* __restrict__ col, __half* __restrict__ g, int N) {
    const int TPN = KP / 4;
    int sub = threadIdx.x / TPN;
    int j   = threadIdx.x % TPN;
    int n = blockIdx.x * NPB + sub;
    if (n >= N) return;
    int c0 = j * 4;
    float acc[H][4];
#pragma unroll
    for (int h = 0; h < H; ++h)
#pragma unroll
        for (int t = 0; t < 4; ++t) acc[h][t] = 0.f;

    int beg = indptr[n], end = indptr[n + 1];
    int i = beg;
    for (; i + 3 < end; i += 4) {
        int s0 = col[i], s1 = col[i + 1], s2 = col[i + 2], s3 = col[i + 3];
        half4v hv0 = *(const half4v*)(hinf + (size_t)s0 * KP + c0);
        half4v hv1 = *(const half4v*)(hinf + (size_t)s1 * KP + c0);
        half4v hv2 = *(const half4v*)(hinf + (size_t)s2 * KP + c0);
        half4v hv3 = *(const half4v*)(hinf + (size_t)s3 * KP + c0);
#pragma unroll
        for (int e = 0; e < 4; ++e) {
            half4v hv = (e == 0) ? hv0 : (e == 1) ? hv1 : (e == 2) ? hv2 : hv3;
            float f[4] = {(float)hv[0], (float)hv[1], (float)hv[2], (float)hv[3]};
            const float2* ap = (const float2*)(palpha + (size_t)(i + e) * H);
#pragma unroll
            for (int h2 = 0; h2 < H / 2; ++h2) {
                float2 aa = ap[h2];
#pragma unroll
                for (int t = 0; t < 4; ++t) {
                    acc[2 * h2 + 0][t] += aa.x * f[t];
                    acc[2 * h2 + 1][t] += aa.y * f[t];
                }
            }
        }
    }
    for (; i < end; ++i) {
        int src = col[i];
        half4v hv = *(const half4v*)(hinf + (size_t)src * KP + c0);
        float f[4] = {(float)hv[0], (float)hv[1], (float)hv[2], (float)hv[3]};
        const float2* ap = (const float2*)(palpha + (size_t)i * H);
#pragma unroll
        for (int h2 = 0; h2 < H / 2; ++h2) {
            float2 aa = ap[h2];
#pragma unroll
            for (int t = 0; t < 4; ++t) {
                acc[2 * h2 + 0][t] += aa.x * f[t];
                acc[2 * h2 + 1][t] += aa.y * f[t];
            }
        }
    }

    __half* gp = g + (size_t)n * (H * KP) + c0;
#pragma unroll
    for (int h = 0; h < H; ++h) {
        float zf = zinv[n * H + h];
        __half2 lo = __floats2half2_rn(acc[h][0] * zf, acc[h][1] * zf);
        __half2 hi = __floats2half2_rn(acc[h][2] * zf, acc[h][3] * zf);
        union { __half2 h2[2]; float2 f2; } u;
        u.h2[0] = lo; u.h2[1] = hi;
        *(float2*)(gp + h * KP) = u.f2;
    }
}

// -------- fused attn+gather via LDS broadcast (layers 1-3) ------------------
// TPN = KP/CH lanes per node (32 or 64; node groups never cross waves).
// Per chunk of EC = TPN/H edges:
//   phase A: lane j -> (e=j/H, h=j%H): p = exp(lrelu(es[src,h]+ed[n,h])),
//            zloc += p, store p -> lds_p[sub][j]  (slot e*H+h = j).
//   phase B: standard pipelined gather; alphas for edge e are broadcast
//            float4 ds_reads from lds_p[sub][e*H..]. DS ops complete in-order
//            per wave -> wave_barrier (free) pins compiler ordering; no
//            __syncthreads needed (divergent degrees safe).
// z reduced over lane classes by shfl_xor strides H..TPN/2 (R23-verified).
template <int H, int KP, int CH, int NPB>
__global__ __launch_bounds__(NPB * (KP / CH)) void gat_fused_lds(
        const __half* __restrict__ hinf, const float* __restrict__ esed,
        const int* __restrict__ indptr, const int* __restrict__ col,
        __half* __restrict__ g, int N) {
    const int TPN = KP / CH;
    const int EC  = TPN / H;
    const int H2  = 2 * H;
    __shared__ float lds_p[NPB][TPN];
    int sub = threadIdx.x / TPN;
    int j   = threadIdx.x % TPN;
    int n = blockIdx.x * NPB + sub;
    if (n >= N) return;
    int e_my = j / H, h_my = j % H;
    int c0 = j * CH;
    float edv = esed[n * H2 + H + h_my];

    float acc[H][CH];
#pragma unroll
    for (int h = 0; h < H; ++h)
#pragma unroll
        for (int t = 0; t < CH; ++t) acc[h][t] = 0.f;
    float zloc = 0.f;

    int beg = indptr[n], deg = indptr[n + 1] - beg;
    for (int base = 0; base < deg; base += EC) {
        // ---- phase A: p values for this chunk -> LDS ----
        int ce = base + e_my;
        float p = 0.f;
        if (ce < deg) {
            int srcm = col[beg + ce];
            p = expf(lrelu02(esed[srcm * H2 + h_my] + edv));
        }
        zloc += p;
        lds_p[sub][j] = p;
        __builtin_amdgcn_wave_barrier();
        // ---- phase B: pipelined gather with LDS-broadcast alphas ----
#pragma unroll
        for (int e = 0; e < EC; ++e) {
            int idx = base + e;
            if (idx < deg) {                  // uniform within node group
                int src = col[beg + idx];
                float f[CH];
                if (CH == 2) {
                    __half2 hv = *(const __half2*)(hinf + (size_t)src * KP + c0);
                    float2 ff = __half22float2(hv);
                    f[0] = ff.x; f[1] = ff.y;
                } else {
                    half4v hv = *(const half4v*)(hinf + (size_t)src * KP + c0);
                    f[0] = (float)hv[0]; f[1] = (float)hv[1];
                    f[2] = (float)hv[2]; f[3] = (float)hv[3];
                }
                const float4* ap = (const float4*)&lds_p[sub][e * H];
#pragma unroll
                for (int q4 = 0; q4 < H / 4; ++q4) {
                    float4 a4 = ap[q4];
#pragma unroll
                    for (int t = 0; t < CH; ++t) {
                        acc[4 * q4 + 0][t] += a4.x * f[t];
                        acc[4 * q4 + 1][t] += a4.y * f[t];
                        acc[4 * q4 + 2][t] += a4.z * f[t];
                        acc[4 * q4 + 3][t] += a4.w * f[t];
                    }
                }
            }
        }
        __builtin_amdgcn_wave_barrier();
    }

    // z: reduce across the EC lanes of each head class
#pragma unroll
    for (int off = H; off < TPN; off <<= 1)
        zloc += __shfl_xor(zloc, off, TPN);
    float zinv_my = (1.f / H) / (zloc + 1e-16f);

    __half* gp = g + (size_t)n * (H * KP) + c0;
#pragma unroll
    for (int h = 0; h < H; ++h) {
        float zf = __shfl(zinv_my, h, TPN);   // lane class h holds z for head h
        if (CH == 2) {
            *(__half2*)(gp + h * KP) =
                __floats2half2_rn(acc[h][0] * zf, acc[h][1] * zf);
        } else {
            __half2 lo = __floats2half2_rn(acc[h][0] * zf, acc[h][1] * zf);
            __half2 hi = __floats2half2_rn(acc[h][2] * zf, acc[h][3] * zf);
            union { __half2 h2[2]; float2 f2; } u;
            u.h2[0] = lo; u.h2[1] = hi;
            *(float2*)(gp + h * KP) = u.f2;
        }
    }
}

// -------- layer 4: fused attention + projected gather + output --------------
template <int NPB>
__global__ __launch_bounds__(NPB * 32) void final_attn(
        const float* __restrict__ eyp, const int* __restrict__ indptr,
        const int* __restrict__ col, const float* __restrict__ b5,
        const unsigned* __restrict__ masks, const float* __restrict__ x,
        float* __restrict__ outp, int N) {
    int sub = threadIdx.x >> 5;
    int j   = threadIdx.x & 31;
    int n = blockIdx.x * NPB + sub;
    if (n >= N) return;
    int h = j >> 1;
    float edv = eyp[(size_t)n * 64 + 16 + h];
    int beg = indptr[n], end = indptr[n + 1];
    float z = 0.f, a = 0.f;
    int i = beg;
    for (; i + 1 < end; i += 2) {
        int s0 = col[i], s1 = col[i + 1];
        const float* r0 = eyp + (size_t)s0 * 64;
        const float* r1 = eyp + (size_t)s1 * 64;
        float es0 = r0[h], y0 = r0[32 + j];
        float es1 = r1[h], y1 = r1[32 + j];
        float p0 = expf(lrelu02(es0 + edv));
        float p1 = expf(lrelu02(es1 + edv));
        z += p0; a += p0 * y0;
        z += p1; a += p1 * y1;
    }
    for (; i < end; ++i) {
        const float* r = eyp + (size_t)col[i] * 64;
        float p = expf(lrelu02(r[h] + edv));
        z += p; a += p * r[32 + j];
    }
    float zf = (1.f / 16.f) / (z + 1e-16f);
    float val = a * zf;
#pragma unroll
    for (int off = 2; off <= 16; off <<= 1) val += __shfl_xor(val, off, 32);
    float other = __shfl_xor(val, 1, 32);        // opposite parity's sum
    if (j == 0) {
        unsigned mk = masks[n];
        float v0 = x[n * 10 + 0] + selu_f(val + b5[0]);
        float v1 = x[n * 10 + 1] + selu_f(other + b5[1]);
        if (mk & 2u) v0 = 0.f; else if (mk & 1u) v0 = 1.f;
        if (mk & 8u) v1 = 1.f; else if (mk & 4u) v1 = 0.f;
        outp[n * 2 + 0] = v0;
        outp[n * 2 + 1] = v1;
    }
}

// ---------------- LDS-staged f16 MFMA GEMM (64x64 tile, BK=64) --------------
#define LDP 72
__global__ __launch_bounds__(256) void gemm_lds(const __half* __restrict__ A,
                                                const unsigned short* __restrict__ Bhi,
                                                const float* __restrict__ bias,
                                                const unsigned* __restrict__ masks,
                                                __half* __restrict__ O16,
                                                int N, int K, int M) {
    __shared__ __half lA[64 * LDP], lB[64 * LDP];
    int tid = threadIdx.x;
    int wave = tid >> 6, lane = tid & 63;
    int ln16 = lane & 15, q = lane >> 4;
    int row0 = blockIdx.x * 64;
    int col0 = blockIdx.y * 64;

    int r0 = tid >> 3, r1 = r0 + 32;
    int ac = (tid & 7) * 8;                      // col offset in halves
    int ga0 = min(row0 + r0, N - 1);
    int ga1 = min(row0 + r1, N - 1);
    const __half* Bp = (const __half*)Bhi;
    const __half* a0p = A + (size_t)ga0 * K + ac;
    const __half* a1p = A + (size_t)ga1 * K + ac;
    const __half* b0p = Bp + (size_t)(col0 + r0) * K + ac;
    const __half* b1p = Bp + (size_t)(col0 + r1) * K + ac;

    half8 ra0 = *(const half8*)(a0p);
    half8 ra1 = *(const half8*)(a1p);
    half8 rb0 = *(const half8*)(b0p);
    half8 rb1 = *(const half8*)(b1p);

    f32x4 acc[4];
#pragma unroll
    for (int j = 0; j < 4; ++j) acc[j] = (f32x4){0.f, 0.f, 0.f, 0.f};

    for (int kc = 0; kc < K; kc += 64) {
        __syncthreads();
        *(half8*)(lA + r0 * LDP + ac) = ra0;
        *(half8*)(lA + r1 * LDP + ac) = ra1;
        *(half8*)(lB + r0 * LDP + ac) = rb0;
        *(half8*)(lB + r1 * LDP + ac) = rb1;
        __syncthreads();
        int kn = kc + 64;
        if (kn < K) {
            ra0 = *(const half8*)(a0p + kn);
            ra1 = *(const half8*)(a1p + kn);
            rb0 = *(const half8*)(b0p + kn);
            rb1 = *(const half8*)(b1p + kn);
        }
#pragma unroll
        for (int kk = 0; kk < 2; ++kk) {
            half8 af = *(const half8*)(lA + (wave * 16 + ln16) * LDP + kk * 32 + q * 8);
#pragma unroll
            for (int j = 0; j < 4; ++j) {
                half8 bf = *(const half8*)(lB + (j * 16 + ln16) * LDP + kk * 32 + q * 8);
                acc[j] = __builtin_amdgcn_mfma_f32_16x16x32_f16(af, bf, acc[j], 0, 0, 0);
            }
        }
    }

#pragma unroll
    for (int j = 0; j < 4; ++j) {
        int cc = col0 + j * 16 + ln16;
        float bv = bias[cc];
#pragma unroll
        for (int r = 0; r < 4; ++r) {
            int rr = row0 + wave * 16 + q * 4 + r;
            if (rr >= N) continue;
            float v = selu_f(acc[j][r] + bv);
            if (cc < 2) {
                unsigned mk = masks[rr];
                if (cc == 0) { if (mk & 2u) v = 0.f; else if (mk & 1u) v = 1.f; }
                else         { if (mk & 8u) v = 1.f; else if (mk & 4u) v = 0.f; }
            }
            O16[(size_t)rr * M + cc] = __float2half(v);
        }
    }
}

// ---------------------------------------------------------------------------
extern "C" void kernel_launch(void* const* d_in, const int* in_sizes, int n_in,
                              void* d_out, int out_size, void* d_ws, size_t ws_size,
                              hipStream_t stream) {
    const float* x   = (const float*)d_in[0];
    const int*   ei  = (const int*)d_in[1];
    const float* cf  = (const float*)d_in[2];
    const float* cw[4] = {(const float*)d_in[3], (const float*)d_in[5],
                          (const float*)d_in[7], (const float*)d_in[9]};
    const float* cb[4] = {(const float*)d_in[4], (const float*)d_in[6],
                          (const float*)d_in[8], (const float*)d_in[10]};
    const float* gw[5], *gas[5], *gad[5], *gb[5];
    for (int i = 0; i < 5; ++i) {
        gw[i]  = (const float*)d_in[11 + 4 * i];
        gas[i] = (const float*)d_in[12 + 4 * i];
        gad[i] = (const float*)d_in[13 + 4 * i];
        gb[i]  = (const float*)d_in[14 + 4 * i];
    }
    const int N = in_sizes[0] / 10;        // 10000
    const int E = in_sizes[1] / 2;         // 160000
    const int EN = E + N;
    const int NB = (N + 255) / 256;        // scan blocks (40)

    // ---- workspace carve-up ----
    char* base = (char*)d_ws;
    size_t off = 0;
    auto alloc = [&](size_t bytes) -> char* {
        char* p = base + off;
        off = (off + bytes + 255) & ~(size_t)255;
        return p;
    };
    float* cfp   = (float*)alloc((size_t)4 * PSZ * 4);
    float* c1p   = (float*)alloc((size_t)16 * PSZ * 4);
    float* c2p   = (float*)alloc((size_t)32 * PSZ * 4);
    float* c3p   = (float*)alloc((size_t)64 * PSZ * 4);
    float* c4p   = (float*)alloc((size_t)24 * PSZ * 4);
    float* gfeat = (float*)alloc(24 * 4);
    __half* hA16 = (__half*)alloc((size_t)N * 256 * 2);
    __half* hB16 = (__half*)alloc((size_t)N * 256 * 2);
    __half* g    = (__half*)alloc((size_t)N * 2048 * 2);
    float* esed  = (float*)alloc((size_t)N * 32 * 4);
    float* eyp   = (float*)alloc((size_t)N * 64 * 4);        // L4 [es|ed|y]
    float* zinv  = (float*)alloc((size_t)N * 16 * 4);
    float* palpha = (float*)alloc((size_t)EN * 16 * 4);      // L0 numerators
    float* wesed = (float*)alloc((size_t)13056 * 4);         // layers 0-3
    float* wcomb = (float*)alloc((size_t)8192 * 4);          // L4 combined weights
    unsigned short* bt = (unsigned short*)alloc((size_t)679936 * 2);  // 4 GEMM layers
    unsigned* masks = (unsigned*)alloc((size_t)N * 4);
    int* cnt    = (int*)alloc((size_t)N * 4);
    int* pref   = (int*)alloc((size_t)N * 4);
    int* bsums  = (int*)alloc(64 * 4);
    int* indptr = (int*)alloc((size_t)(N + 1) * 4);
    int* cursor = (int*)alloc((size_t)N * 4);
    int* col    = (int*)alloc((size_t)EN * 4);
    (void)ws_size; // ~78 MB

    // ---- one-shot fused weight prep (all 5 layers) ----
    prep_all<<<251, 256, 0, stream>>>(gw[0], gw[1], gw[2], gw[3], gw[4],
                                      gas[0], gas[1], gas[2], gas[3], gas[4],
                                      gad[0], gad[1], gad[2], gad[3], gad[4],
                                      bt, wesed, wcomb);

    // ---- CNN (padded layout; single memset zeroes all borders) ----
    hipMemsetAsync(cfp, 0, (size_t)140 * PSZ * 4, stream);
    pad_input<<<(4 * 4096 + 255) / 256, 256, 0, stream>>>(cf, cfp);
    conv3x3_pad<4><<<dim3(16, 16), 256, 0, stream>>>(cfp, cw[0], cb[0], c1p);
    conv3x3_pad<16><<<dim3(16, 32), 256, 0, stream>>>(c1p, cw[1], cb[1], c2p);
    conv3x3_pad<32><<<dim3(16, 64), 256, 0, stream>>>(c2p, cw[2], cb[2], c3p);
    conv3x3_pad<64><<<dim3(16, 24), 256, 0, stream>>>(c3p, cw[3], cb[3], c4p);
    avgpool_c<<<24, 256, 0, stream>>>(c4p, gfeat);

    // ---- h0 (padded to 48, fp16) + masks ----
    build_h0<<<(N + 255) / 256, 256, 0, stream>>>(x, gfeat, hA16, masks, N);

    // ---- CSR by dst (incl self loops), parallel scan ----
    hipMemsetAsync(cnt, 0, (size_t)N * 4, stream);
    count_dst<<<(EN + 255) / 256, 256, 0, stream>>>(ei, cnt, E, N);
    scan_blocks<<<NB, 256, 0, stream>>>(cnt, pref, bsums, N);
    scan_sums<<<1, 64, 0, stream>>>(bsums, NB);
    scan_apply<<<NB, 256, 0, stream>>>(pref, bsums, indptr, cursor, N, EN);
    scatter_edges<<<(EN + 255) / 256, 256, 0, stream>>>(ei, cursor, col, E, N);

    // ---- GAT layers ----
    const int Hs[5] = {8, 16, 8, 8, 16};
    const int Cs[5] = {64, 128, 256, 128, 2};
    const int Kp[5] = {48, 64, 128, 256, 128};
    const int btOffA[5] = {0, 24576, 155648, 417792, 0};
    const int weOffA[5] = {0, 768, 2816, 4864, 8960};

    const __half* hin16 = hA16;
    __half* hout16[4]  = {hB16, hA16, hB16, hA16};

    for (int lyr = 0; lyr < 5; ++lyr) {
        int KP = Kp[lyr], H = Hs[lyr], C = Cs[lyr];
        int KA = H * KP;
        if (lyr == 4) {
            // project-first fused final layer
            esed_kernel<<<(N * 64 + 255) / 256, 256, 0, stream>>>(hin16, wcomb, eyp,
                                                                  N, 128, 64);
            final_attn<8><<<(N + 7) / 8, 256, 0, stream>>>(eyp, indptr, col, gb[4],
                                                           masks, x, (float*)d_out, N);
            break;
        }
        esed_kernel<<<(N * 2 * H + 255) / 256, 256, 0, stream>>>(hin16, wesed + weOffA[lyr],
                                                                 esed, N, KP, 2 * H);
        if (lyr == 0) {
            attn_kernel<<<(N * H + 255) / 256, 256, 0, stream>>>(esed, indptr, col,
                                                                 palpha, zinv, N, H);
            gat_gather4<8, 48, 20><<<(N + 19) / 20, 240, 0, stream>>>(
                hin16, palpha, zinv, indptr, col, g, N);
        } else if (lyr == 1) {
            gat_fused_lds<16, 64, 2, 8><<<(N + 7) / 8, 256, 0, stream>>>(
                hin16, esed, indptr, col, g, N);
        } else if (lyr == 2) {
            gat_fused_lds<8, 128, 4, 8><<<(N + 7) / 8, 256, 0, stream>>>(
                hin16, esed, indptr, col, g, N);
        } else {
            gat_fused_lds<8, 256, 4, 4><<<(N + 3) / 4, 256, 0, stream>>>(
                hin16, esed, indptr, col, g, N);
        }

        const unsigned short* btL = bt + btOffA[lyr];
        int gx = (N + 63) / 64;        // 157
        gemm_lds<<<dim3(gx, C / 64), 256, 0, stream>>>(g, btL, gb[lyr], masks,
                                                       hout16[lyr], N, KA, C);
        hin16 = hout16[lyr];
    }
}